// Round 1
// baseline (3857.222 us; speedup 1.0000x reference)
//
#include <hip/hip_runtime.h>
#include <math.h>

// ---------------- workspace layout (float-element offsets) ----------------
static const size_t WS_FEA1  = 0;          // 4*64*160*160 = 6,553,600
static const size_t WS_FEA2  = 6553600;    // 4*128*80*80  = 3,276,800
static const size_t WS_FEA3L = 9830400;    // 4*256*40*40  = 1,638,400
static const size_t WS_FEA3U = 11468800;   // 1,638,400
static const size_t WS_ZLS   = 13107200;   // 4*2*40*40 = 12,800
static const size_t WS_ZUL   = 13120000;   // 12,800
static const size_t WS_FEAT  = 13132800;   // 12800*128 = 1,638,400
static const size_t WS_LAB   = 14771200;   // 12,800 (int32)
static const size_t WS_PART  = 14784000;   // 64*4*100*4 = 102,400
static const size_t WS_ACC   = 14886400;   // 16 floats: 0 supN 1 supD 2 ent 3 consN 4 consD 5 contrN 6 contrD
static const size_t WS_FC    = 14886416;   // 64 floats (per-patch positive-label count)
// total: 14,886,480 floats = 59.5 MB

// ---------------- conv 3x3 stride 2, SAME (pad lo=0 hi=1), + ReLU ----------------
__global__ __launch_bounds__(256) void conv3x3_s2_relu(
    const float* __restrict__ in, const float* __restrict__ w,
    float* __restrict__ out, int Ci, int H, int W, int Co)
{
    int OH = H >> 1, OW = W >> 1;
    int sp = blockIdx.x * 256 + threadIdx.x;
    if (sp >= OH * OW) return;
    int co = blockIdx.y;
    int n  = blockIdx.z;
    int oy = sp / OW, ox = sp % OW;
    int iy0 = oy * 2, ix0 = ox * 2;
    const float* wp = w + (size_t)co * Ci * 9;
    const float* ip = in + (size_t)n * Ci * H * W;
    bool xe = (ix0 + 2 < W);
    float acc = 0.f;
    for (int ci = 0; ci < Ci; ++ci) {
        const float* ib = ip + (size_t)ci * H * W;
        const float* wc = wp + ci * 9;
        #pragma unroll
        for (int ky = 0; ky < 3; ++ky) {
            int iy = iy0 + ky;
            if (iy < H) {
                const float* r = ib + (size_t)iy * W + ix0;
                float v0 = r[0];
                float v1 = r[1];                 // ix0+1 <= W-1 always
                float v2 = xe ? r[2] : 0.f;
                acc += v0 * wc[ky*3+0] + v1 * wc[ky*3+1] + v2 * wc[ky*3+2];
            }
        }
    }
    out[(((size_t)n * Co + co) * OH + oy) * OW + ox] = fmaxf(acc, 0.f);
}

// ---------------- 1x1 classifier conv: 256 -> 2 (+bias) ----------------
__global__ __launch_bounds__(256) void conv1x1_cls(
    const float* __restrict__ fea, const float* __restrict__ Wc,
    const float* __restrict__ bc, float* __restrict__ z, int total)
{
    int idx = blockIdx.x * 256 + threadIdx.x;
    if (idx >= total) return;
    int r = idx % 1600;
    int c = (idx / 1600) & 1;
    int n = idx / 3200;
    const float* f = fea + (size_t)n * 256 * 1600 + r;
    const float* w = Wc + c * 256;
    float acc = bc[c];
    for (int ci = 0; ci < 256; ci += 4) {
        acc += f[(ci+0)*1600] * w[ci+0] + f[(ci+1)*1600] * w[ci+1]
             + f[(ci+2)*1600] * w[ci+2] + f[(ci+3)*1600] * w[ci+3];
    }
    z[idx] = acc;
}

// ---------------- supervised CE over bilinear-upsampled logits ----------------
__global__ __launch_bounds__(256) void loss_sup_kernel(
    const float* __restrict__ zs /*4,2,40,40*/, const int* __restrict__ y,
    float* __restrict__ acc)
{
    int idx = blockIdx.x * 256 + threadIdx.x;   // 409600 total
    int n  = idx / 102400;
    int r  = idx % 102400;
    int oy = r / 320, ox = r % 320;
    const float step = 39.0f / 319.0f;
    float ty = (float)oy * step, tx = (float)ox * step;
    int y0 = (int)floorf(ty), x0 = (int)floorf(tx);
    int y1 = min(y0 + 1, 39), x1 = min(x0 + 1, 39);
    float wy = ty - (float)y0, wx = tx - (float)x0;
    const float* base = zs + (size_t)n * 3200;
    float z[2];
    #pragma unroll
    for (int c = 0; c < 2; ++c) {
        const float* pl = base + c * 1600;
        float v00 = pl[y0*40 + x0], v01 = pl[y0*40 + x1];
        float v10 = pl[y1*40 + x0], v11 = pl[y1*40 + x1];
        float top = v00 * (1.f - wx) + v01 * wx;
        float bot = v10 * (1.f - wx) + v11 * wx;
        z[c] = top * (1.f - wy) + bot * wy;
    }
    int lab = y[idx];
    bool valid = (lab != 255);
    int sl = min(max(lab, 0), 1);
    float mz  = fmaxf(z[0], z[1]);
    float lse = mz + logf(expf(z[0]-mz) + expf(z[1]-mz));
    float nll = lse - z[sl];
    float vn = valid ? nll : 0.f;
    float vd = valid ? 1.f : 0.f;
    #pragma unroll
    for (int off = 32; off; off >>= 1) { vn += __shfl_down(vn, off); vd += __shfl_down(vd, off); }
    if ((threadIdx.x & 63) == 0) { atomicAdd(&acc[0], vn); atomicAdd(&acc[1], vd); }
}

// ---------------- unlabeled small losses + pseudo labels + patch counts ----------------
__global__ __launch_bounds__(256) void ul_small_kernel(
    const float* __restrict__ z_ul, const float* __restrict__ z_ema,
    int* __restrict__ lab_all, float* __restrict__ acc, float* __restrict__ fc_cnt)
{
    int idx = blockIdx.x * 256 + threadIdx.x;   // 6400 total
    int n = idx / 1600;
    int r = idx % 1600;
    int yy = r / 40, xx = r % 40;
    float z0 = z_ul[(size_t)n*3200 + r], z1 = z_ul[(size_t)n*3200 + 1600 + r];
    float m = fmaxf(z0, z1);
    float e0 = expf(z0 - m), e1 = expf(z1 - m);
    float lse = m + logf(e0 + e1);
    float lp0 = z0 - lse, lp1 = z1 - lse;
    float p0 = expf(lp0), p1 = expf(lp1);
    float ent = -(p0*lp0 + p1*lp1);
    int pl = (z1 > z0) ? 1 : 0;
    float ze0 = z_ema[(size_t)n*3200 + r], ze1 = z_ema[(size_t)n*3200 + 1600 + r];
    float me = fmaxf(ze0, ze1);
    float f0 = expf(ze0 - me), f1 = expf(ze1 - me);
    float maxp = 1.f / (f0 + f1);
    int ple = (ze1 > ze0) ? 1 : 0;
    bool mask = (maxp > 0.6f);
    float nll = lse - (ple ? z1 : z0);

    int pi = yy / 10, hi = yy % 10, pj = xx / 10, wi = xx % 10;
    int patch = (pi*4 + pj)*4 + n;
    int row = patch * 100 + hi*10 + wi;
    lab_all[row]        = pl;
    lab_all[6400 + row] = ple;
    atomicAdd(&fc_cnt[patch], (float)pl);

    float cn = mask ? nll : 0.f;
    float cd = mask ? 1.f : 0.f;
    #pragma unroll
    for (int off = 32; off; off >>= 1) {
        ent += __shfl_down(ent, off);
        cn  += __shfl_down(cn, off);
        cd  += __shfl_down(cd, off);
    }
    if ((threadIdx.x & 63) == 0) {
        atomicAdd(&acc[2], ent);
        atomicAdd(&acc[3], cn);
        atomicAdd(&acc[4], cd);
    }
}

// ---------------- projector 1x1 conv + L2 normalize + scatter to patch layout ----------------
__global__ __launch_bounds__(128) void proj_kernel(
    const float* __restrict__ fea /*4,256,40,40*/, const float* __restrict__ Wp,
    float* __restrict__ feat_all)
{
    int pix = blockIdx.x;          // 0..6399
    int n = pix / 1600, r = pix % 1600;
    int yy = r / 40, xx = r % 40;
    __shared__ float fv[256];
    __shared__ float wsum[2];
    int t = threadIdx.x;
    for (int ci = t; ci < 256; ci += 128)
        fv[ci] = fea[((size_t)(n*256 + ci)) * 1600 + r];
    __syncthreads();
    const float* w = Wp + (size_t)t * 256;
    float acc = 0.f;
    for (int ci = 0; ci < 256; ci += 4) {
        float4 wv = *(const float4*)&w[ci];
        acc += wv.x*fv[ci] + wv.y*fv[ci+1] + wv.z*fv[ci+2] + wv.w*fv[ci+3];
    }
    float sq = acc * acc;
    #pragma unroll
    for (int off = 32; off; off >>= 1) sq += __shfl_down(sq, off);
    if ((t & 63) == 0) wsum[t >> 6] = sq;
    __syncthreads();
    float norm = sqrtf(wsum[0] + wsum[1]);
    float scale = 1.f / fmaxf(norm, 1e-12f);
    int pi = yy/10, hi = yy%10, pj = xx/10, wi = xx%10;
    int row = ((pi*4 + pj)*4 + n)*100 + hi*10 + wi;
    feat_all[(size_t)row * 128 + t] = acc * scale;
}

// ---------------- scatter EMA projections into feat_all second half ----------------
__global__ __launch_bounds__(256) void ema_scatter(
    const float* __restrict__ ema /*4,128,40,40*/, float* __restrict__ feat_all)
{
    int idx = blockIdx.x * 256 + threadIdx.x;   // 819200
    int xx = idx % 40;
    int yy = (idx / 40) % 40;
    int c  = (idx / 1600) % 128;
    int n  = idx / 204800;
    int pi = yy/10, hi = yy%10, pj = xx/10, wi = xx%10;
    int row = ((pi*4 + pj)*4 + n)*100 + hi*10 + wi;
    feat_all[(size_t)(6400 + row) * 128 + c] = ema[idx];
}

// ---------------- contrastive: streaming log-softmax GEMM ----------------
// grid (4 j-splits, 64 patches) x 256 threads. Per wave: 25 anchors; per lane: 2 j-cols.
__global__ __launch_bounds__(256, 1) void contrast_kernel(
    const float* __restrict__ feat_all, const int* __restrict__ lab_all,
    float* __restrict__ partials)
{
    int js = blockIdx.x;  // 0..3
    int p  = blockIdx.y;  // 0..63
    int t = threadIdx.x;
    int lane = t & 63;
    int wv = t >> 6;

    __shared__ float anch[100 * 128];    // 51,200 B
    __shared__ float feat[128 * 132];    // 67,584 B (row pad -> conflict-free b128)
    __shared__ int   labA[100];

    for (int idx4 = t; idx4 < 3200; idx4 += 256) {     // anchors: 100 rows x 32 float4
        int a = idx4 >> 5, c4 = idx4 & 31;
        *(float4*)&anch[a*128 + c4*4] =
            *(const float4*)&feat_all[((size_t)(p*100 + a))*128 + c4*4];
    }
    if (t < 100) labA[t] = lab_all[p*100 + t];

    int jbase = js * 3200;
    float m[25], s[25], Sp[25], cn[25];
    #pragma unroll
    for (int k = 0; k < 25; ++k) { m[k] = -1e30f; s[k] = 0.f; Sp[k] = 0.f; cn[k] = 0.f; }

    int abase = wv * 25;
    for (int tile = 0; tile < 25; ++tile) {
        __syncthreads();   // previous-tile reads done (and anchors staged for tile 0)
        for (int idx4 = t; idx4 < 4096; idx4 += 256) { // 128 rows x 32 float4
            int j = idx4 >> 5, c4 = idx4 & 31;
            *(float4*)&feat[j*132 + c4*4] =
                *(const float4*)&feat_all[((size_t)(jbase + tile*128 + j))*128 + c4*4];
        }
        __syncthreads();

        int j0 = jbase + tile*128 + lane;
        int lj0 = lab_all[j0];
        int lj1 = lab_all[j0 + 64];

        float dot0[25], dot1[25];
        #pragma unroll
        for (int k = 0; k < 25; ++k) { dot0[k] = 0.f; dot1[k] = 0.f; }

        for (int c4 = 0; c4 < 32; ++c4) {
            float4 ff0 = *(float4*)&feat[lane*132 + c4*4];
            float4 ff1 = *(float4*)&feat[(lane + 64)*132 + c4*4];
            #pragma unroll
            for (int k = 0; k < 25; ++k) {
                float4 av = *(float4*)&anch[(abase + k)*128 + c4*4];
                dot0[k] += av.x*ff0.x + av.y*ff0.y + av.z*ff0.z + av.w*ff0.w;
                dot1[k] += av.x*ff1.x + av.y*ff1.y + av.z*ff1.z + av.w*ff1.w;
            }
        }
        #pragma unroll
        for (int k = 0; k < 25; ++k) {
            int la = labA[abase + k];
            float l0 = dot0[k] * 2.0f;   // 1/TEMP
            float l1 = dot1[k] * 2.0f;
            float mx = fmaxf(m[k], fmaxf(l0, l1));
            s[k] = s[k]*expf(m[k]-mx) + expf(l0-mx) + expf(l1-mx);
            m[k] = mx;
            if (lj0 == la) { Sp[k] += l0; cn[k] += 1.f; }
            if (lj1 == la) { Sp[k] += l1; cn[k] += 1.f; }
        }
    }

    // wave-level merge of per-lane online stats, one anchor at a time
    #pragma unroll
    for (int k = 0; k < 25; ++k) {
        float mm = m[k], ss = s[k], pp = Sp[k], cc = cn[k];
        #pragma unroll
        for (int off = 32; off; off >>= 1) {
            float mo = __shfl_down(mm, off);
            float so = __shfl_down(ss, off);
            float po = __shfl_down(pp, off);
            float co = __shfl_down(cc, off);
            float mx = fmaxf(mm, mo);
            ss = ss*expf(mm-mx) + so*expf(mo-mx);
            mm = mx; pp += po; cc += co;
        }
        if (lane == 0) {
            float* dst = &partials[(((size_t)p*4 + js)*100 + (abase + k)) * 4];
            dst[0] = mm; dst[1] = ss; dst[2] = pp; dst[3] = cc;
        }
    }
}

// ---------------- merge j-splits, per-patch mean, include weighting ----------------
__global__ __launch_bounds__(128) void merge_kernel(
    const float* __restrict__ partials, const float* __restrict__ fc_cnt,
    float* __restrict__ acc)
{
    int p = blockIdx.x;
    int t = threadIdx.x;
    float pa = 0.f;
    if (t < 100) {
        float mm = -1e30f, ss = 0.f, pp = 0.f, cc = 0.f;
        for (int js = 0; js < 4; ++js) {
            const float* src = &partials[(((size_t)p*4 + js)*100 + t) * 4];
            float m2 = src[0], s2 = src[1];
            float mx = fmaxf(mm, m2);
            ss = ss*expf(mm-mx) + s2*expf(m2-mx);
            mm = mx; pp += src[2]; cc += src[3];
        }
        float lse = mm + logf(ss);
        pa = lse - pp / fmaxf(cc, 1.f);
    }
    #pragma unroll
    for (int off = 32; off; off >>= 1) pa += __shfl_down(pa, off);
    __shared__ float w2[2];
    if ((t & 63) == 0) w2[t >> 6] = pa;
    __syncthreads();
    if (t == 0) {
        float loss_p = (w2[0] + w2[1]) / 100.f;
        float fc = fc_cnt[p] / 100.f;
        float inc = ((fc > 0.1f) && (fc < 0.9f)) ? 0.f : 1.f;
        atomicAdd(&acc[5], loss_p * inc);
        atomicAdd(&acc[6], inc);
    }
}

// ---------------- final combine ----------------
__global__ void final_kernel(const float* __restrict__ acc,
                             const int* __restrict__ epoch_p,
                             float* __restrict__ out)
{
    if (threadIdx.x == 0 && blockIdx.x == 0) {
        float loss_sup = acc[0] / fmaxf(acc[1], 1.f);
        int epoch = *epoch_p;
        float loss = loss_sup;
        if (epoch >= 5) {
            float contr = acc[5] / fmaxf(acc[6], 1.f);
            float cons  = acc[3] / fmaxf(acc[4], 1.f);
            float ent   = acc[2] / 6400.f;
            float ramp  = fminf(fmaxf((float)epoch / 40.f, 0.f), 1.f);
            float d = 1.f - ramp;
            float cons_w = 1.0f * expf(-5.f * d * d);
            loss = loss_sup + 0.1f * contr + cons_w * cons + 0.01f * ent;
        }
        out[0] = loss;
    }
}

extern "C" void kernel_launch(void* const* d_in, const int* in_sizes, int n_in,
                              void* d_out, int out_size, void* d_ws, size_t ws_size,
                              hipStream_t stream)
{
    const float* x_l      = (const float*)d_in[0];
    const int*   y_l      = (const int*)  d_in[1];
    const float* x_ul     = (const float*)d_in[2];
    const int*   epoch    = (const int*)  d_in[3];
    const float* proj_ema = (const float*)d_in[4];
    const float* z_ema    = (const float*)d_in[5];
    const float* W1       = (const float*)d_in[6];
    const float* W2       = (const float*)d_in[7];
    const float* W3       = (const float*)d_in[8];
    const float* Wc       = (const float*)d_in[9];
    const float* bc       = (const float*)d_in[10];
    const float* Wp       = (const float*)d_in[11];
    float* out = (float*)d_out;
    float* ws  = (float*)d_ws;

    float* fea1   = ws + WS_FEA1;
    float* fea2   = ws + WS_FEA2;
    float* fea3l  = ws + WS_FEA3L;
    float* fea3u  = ws + WS_FEA3U;
    float* zls    = ws + WS_ZLS;
    float* zul    = ws + WS_ZUL;
    float* featA  = ws + WS_FEAT;
    int*   labA   = (int*)(ws + WS_LAB);
    float* part   = ws + WS_PART;
    float* acc    = ws + WS_ACC;
    float* fc     = ws + WS_FC;

    // zero the accumulators + per-patch counts each call
    hipMemsetAsync(acc, 0, (16 + 64) * sizeof(float), stream);

    // ---- labeled branch ----
    conv3x3_s2_relu<<<dim3(100, 64, 4), 256, 0, stream>>>(x_l, W1, fea1, 3, 320, 320, 64);
    conv3x3_s2_relu<<<dim3(25, 128, 4), 256, 0, stream>>>(fea1, W2, fea2, 64, 160, 160, 128);
    conv3x3_s2_relu<<<dim3(7, 256, 4), 256, 0, stream>>>(fea2, W3, fea3l, 128, 80, 80, 256);
    conv1x1_cls<<<50, 256, 0, stream>>>(fea3l, Wc, bc, zls, 12800);
    loss_sup_kernel<<<1600, 256, 0, stream>>>(zls, y_l, acc);

    // ---- unlabeled branch ----
    conv3x3_s2_relu<<<dim3(100, 64, 4), 256, 0, stream>>>(x_ul, W1, fea1, 3, 320, 320, 64);
    conv3x3_s2_relu<<<dim3(25, 128, 4), 256, 0, stream>>>(fea1, W2, fea2, 64, 160, 160, 128);
    conv3x3_s2_relu<<<dim3(7, 256, 4), 256, 0, stream>>>(fea2, W3, fea3u, 128, 80, 80, 256);
    conv1x1_cls<<<50, 256, 0, stream>>>(fea3u, Wc, bc, zul, 12800);

    proj_kernel<<<6400, 128, 0, stream>>>(fea3u, Wp, featA);
    ema_scatter<<<3200, 256, 0, stream>>>(proj_ema, featA);
    ul_small_kernel<<<25, 256, 0, stream>>>(zul, z_ema, labA, acc, fc);

    contrast_kernel<<<dim3(4, 64), 256, 0, stream>>>(featA, labA, part);
    merge_kernel<<<64, 128, 0, stream>>>(part, fc, acc);
    final_kernel<<<1, 64, 0, stream>>>(acc, epoch, out);
}

// Round 2
// 1166.626 us; speedup vs baseline: 3.3063x; 3.3063x over previous
//
#include <hip/hip_runtime.h>
#include <math.h>

typedef unsigned short u16;
typedef __attribute__((ext_vector_type(8))) short bf16x8;
typedef __attribute__((ext_vector_type(4))) float f32x4;

// ---------------- workspace layout (float-element offsets) ----------------
static const size_t WS_FEA1  = 0;          // 4*64*160*160 = 6,553,600
static const size_t WS_FEA2  = 6553600;    // 4*128*80*80  = 3,276,800
static const size_t WS_FEA3L = 9830400;    // 4*256*40*40  = 1,638,400
static const size_t WS_FEA3U = 11468800;   // 1,638,400
static const size_t WS_ZLS   = 13107200;   // 12,800
static const size_t WS_ZUL   = 13120000;   // 12,800
static const size_t WS_FEATB = 13132800;   // 12800*128 bf16 = 819,200 float slots
static const size_t WS_LAB   = 13952000;   // 12,800 int
static const size_t WS_PART  = 13964800;   // 64*8*112*3 = 172,032
static const size_t WS_ACC   = 14136832;   // 16 floats (acc[7] = maxnorm2 bits)
static const size_t WS_FC    = 14136848;   // 64 floats
// total ~56.5 MB (< round-1's 59.5 MB footprint)

__device__ inline u16 f2bf(float x) {
    unsigned int u = __float_as_uint(x);
    unsigned int r = u + 0x7fffu + ((u >> 16) & 1u);
    return (u16)(r >> 16);
}

// ---------------- conv 3x3 stride 2, SAME (pad lo=0 hi=1), + ReLU ----------------
// register-tiled: 4 co x 4 ox per thread
__global__ __launch_bounds__(256) void conv3x3_s2_relu_t(
    const float* __restrict__ in, const float* __restrict__ w,
    float* __restrict__ out, int Ci, int H, int W, int Co)
{
    int OH = H >> 1, OW = W >> 1;
    int QW = OW >> 2;
    int nq = OH * QW;
    int q = blockIdx.x * 256 + threadIdx.x;
    if (q >= nq) return;
    int co0 = blockIdx.y * 4;
    int n = blockIdx.z;
    int oy = q / QW, tx = q % QW;
    int ix0 = tx * 8;
    int iy0 = oy * 2;
    float acc[4][4] = {};
    const float* ip = in + ((size_t)n * Ci) * H * W;
    for (int ci = 0; ci < Ci; ++ci) {
        const float* plane = ip + (size_t)ci * H * W;
        float wr[4][9];
        #pragma unroll
        for (int cc = 0; cc < 4; ++cc) {
            const float* wp = w + ((size_t)(co0 + cc) * Ci + ci) * 9;
            #pragma unroll
            for (int k = 0; k < 9; ++k) wr[cc][k] = wp[k];
        }
        #pragma unroll
        for (int ky = 0; ky < 3; ++ky) {
            int iy = iy0 + ky;
            if (iy < H) {
                const float* r = plane + (size_t)iy * W + ix0;
                float4 a = *(const float4*)r;
                float4 b = *(const float4*)(r + 4);
                float x8 = (ix0 + 8 < W) ? r[8] : 0.f;
                float x[9] = {a.x,a.y,a.z,a.w,b.x,b.y,b.z,b.w,x8};
                #pragma unroll
                for (int cc = 0; cc < 4; ++cc) {
                    #pragma unroll
                    for (int qq = 0; qq < 4; ++qq)
                        acc[cc][qq] += x[2*qq]   * wr[cc][ky*3+0]
                                     + x[2*qq+1] * wr[cc][ky*3+1]
                                     + x[2*qq+2] * wr[cc][ky*3+2];
                }
            }
        }
    }
    #pragma unroll
    for (int cc = 0; cc < 4; ++cc) {
        float4 o = make_float4(fmaxf(acc[cc][0],0.f), fmaxf(acc[cc][1],0.f),
                               fmaxf(acc[cc][2],0.f), fmaxf(acc[cc][3],0.f));
        *(float4*)&out[(((size_t)n * Co + co0 + cc) * OH + oy) * OW + tx*4] = o;
    }
}

// ---------------- 1x1 classifier conv (coalesced: one pixel/thread, both classes) ----------------
__global__ __launch_bounds__(256) void conv1x1_cls(
    const float* __restrict__ fea, const float* __restrict__ Wc,
    const float* __restrict__ bc, float* __restrict__ z)
{
    int idx = blockIdx.x * 256 + threadIdx.x;   // 6400
    int n = idx / 1600, r = idx % 1600;
    const float* f = fea + (size_t)n * 256 * 1600 + r;
    float a0 = 0.f, a1 = 0.f;
    for (int ci = 0; ci < 256; ++ci) {
        float v = f[(size_t)ci * 1600];
        a0 += v * Wc[ci];
        a1 += v * Wc[256 + ci];
    }
    z[(size_t)n*3200 + r]        = a0 + bc[0];
    z[(size_t)n*3200 + 1600 + r] = a1 + bc[1];
}

// ---------------- supervised CE over bilinear-upsampled logits ----------------
__global__ __launch_bounds__(256) void loss_sup_kernel(
    const float* __restrict__ zs, const int* __restrict__ y,
    float* __restrict__ acc)
{
    int idx = blockIdx.x * 256 + threadIdx.x;   // 409600
    int n  = idx / 102400;
    int r  = idx % 102400;
    int oy = r / 320, ox = r % 320;
    const float step = 39.0f / 319.0f;
    float ty = (float)oy * step, tx = (float)ox * step;
    int y0 = (int)floorf(ty), x0 = (int)floorf(tx);
    int y1 = min(y0 + 1, 39), x1 = min(x0 + 1, 39);
    float wy = ty - (float)y0, wx = tx - (float)x0;
    const float* base = zs + (size_t)n * 3200;
    float z[2];
    #pragma unroll
    for (int c = 0; c < 2; ++c) {
        const float* pl = base + c * 1600;
        float v00 = pl[y0*40 + x0], v01 = pl[y0*40 + x1];
        float v10 = pl[y1*40 + x0], v11 = pl[y1*40 + x1];
        float top = v00 * (1.f - wx) + v01 * wx;
        float bot = v10 * (1.f - wx) + v11 * wx;
        z[c] = top * (1.f - wy) + bot * wy;
    }
    int lab = y[idx];
    bool valid = (lab != 255);
    int sl = min(max(lab, 0), 1);
    float mz  = fmaxf(z[0], z[1]);
    float lse = mz + logf(expf(z[0]-mz) + expf(z[1]-mz));
    float nll = lse - z[sl];
    float vn = valid ? nll : 0.f;
    float vd = valid ? 1.f : 0.f;
    #pragma unroll
    for (int off = 32; off; off >>= 1) { vn += __shfl_down(vn, off); vd += __shfl_down(vd, off); }
    if ((threadIdx.x & 63) == 0) { atomicAdd(&acc[0], vn); atomicAdd(&acc[1], vd); }
}

// ---------------- unlabeled small losses + pseudo labels + patch counts ----------------
__global__ __launch_bounds__(256) void ul_small_kernel(
    const float* __restrict__ z_ul, const float* __restrict__ z_ema,
    int* __restrict__ lab_all, float* __restrict__ acc, float* __restrict__ fc_cnt)
{
    int idx = blockIdx.x * 256 + threadIdx.x;   // 6400
    int n = idx / 1600;
    int r = idx % 1600;
    int yy = r / 40, xx = r % 40;
    float z0 = z_ul[(size_t)n*3200 + r], z1 = z_ul[(size_t)n*3200 + 1600 + r];
    float m = fmaxf(z0, z1);
    float e0 = expf(z0 - m), e1 = expf(z1 - m);
    float lse = m + logf(e0 + e1);
    float lp0 = z0 - lse, lp1 = z1 - lse;
    float p0 = expf(lp0), p1 = expf(lp1);
    float ent = -(p0*lp0 + p1*lp1);
    int pl = (z1 > z0) ? 1 : 0;
    float ze0 = z_ema[(size_t)n*3200 + r], ze1 = z_ema[(size_t)n*3200 + 1600 + r];
    float me = fmaxf(ze0, ze1);
    float f0 = expf(ze0 - me), f1 = expf(ze1 - me);
    float maxp = 1.f / (f0 + f1);
    int ple = (ze1 > ze0) ? 1 : 0;
    bool mask = (maxp > 0.6f);
    float nll = lse - (ple ? z1 : z0);

    int pi = yy / 10, hi = yy % 10, pj = xx / 10, wi = xx % 10;
    int patch = (pi*4 + pj)*4 + n;
    int row = patch * 100 + hi*10 + wi;
    lab_all[row]        = pl;
    lab_all[6400 + row] = ple;
    atomicAdd(&fc_cnt[patch], (float)pl);

    float cn = mask ? nll : 0.f;
    float cd = mask ? 1.f : 0.f;
    #pragma unroll
    for (int off = 32; off; off >>= 1) {
        ent += __shfl_down(ent, off);
        cn  += __shfl_down(cn, off);
        cd  += __shfl_down(cd, off);
    }
    if ((threadIdx.x & 63) == 0) {
        atomicAdd(&acc[2], ent);
        atomicAdd(&acc[3], cn);
        atomicAdd(&acc[4], cd);
    }
}

// ---------------- projector GEMM: wave = 32 out-channels, lane = pixel ----------------
__global__ __launch_bounds__(256) void proj_gemm(
    const float* __restrict__ fea, const float* __restrict__ Wp,
    u16* __restrict__ feat)
{
    int n = blockIdx.y;
    int px0 = blockIdx.x * 64;
    int lane = threadIdx.x & 63;
    int wv = threadIdx.x >> 6;
    int ch0 = wv * 32;
    int px = px0 + lane;
    const float* f = fea + (size_t)n * 256 * 1600 + px;
    float acc[32] = {};
    for (int ci0 = 0; ci0 < 256; ci0 += 4) {
        float v0 = f[(size_t)(ci0+0)*1600];
        float v1 = f[(size_t)(ci0+1)*1600];
        float v2 = f[(size_t)(ci0+2)*1600];
        float v3 = f[(size_t)(ci0+3)*1600];
        #pragma unroll
        for (int c = 0; c < 32; ++c) {
            float4 wv4 = *(const float4*)&Wp[(size_t)(ch0 + c)*256 + ci0];
            acc[c] += v0*wv4.x + v1*wv4.y + v2*wv4.z + v3*wv4.w;
        }
    }
    float sq = 0.f;
    #pragma unroll
    for (int c = 0; c < 32; ++c) sq += acc[c]*acc[c];
    __shared__ float red[4][64];
    red[wv][lane] = sq;
    __syncthreads();
    float tot = red[0][lane] + red[1][lane] + red[2][lane] + red[3][lane];
    float scale = 1.f / fmaxf(sqrtf(tot), 1e-12f);
    int yy = px / 40, xx = px % 40;
    int row = ((yy/10*4 + xx/10)*4 + n)*100 + (yy%10)*10 + (xx%10);
    u16* dst = feat + (size_t)row * 128 + ch0;
    #pragma unroll
    for (int c2 = 0; c2 < 16; ++c2) {
        unsigned int pk = (unsigned int)f2bf(acc[2*c2]*scale)
                        | ((unsigned int)f2bf(acc[2*c2+1]*scale) << 16);
        *(unsigned int*)&dst[c2*2] = pk;
    }
}

// ---------------- EMA scatter -> bf16 feat + per-row norm max ----------------
__global__ __launch_bounds__(256) void ema_scatter(
    const float* __restrict__ ema, u16* __restrict__ feat,
    unsigned int* __restrict__ maxn)
{
    int t = threadIdx.x;
    int c = t & 127, s = t >> 7;
    int px = blockIdx.x * 2 + s;      // 0..6399
    int n = px / 1600, r = px % 1600;
    float v = ema[((size_t)n * 128 + c) * 1600 + r];
    int yy = r / 40, xx = r % 40;
    int row = 6400 + ((yy/10*4 + xx/10)*4 + n)*100 + (yy%10)*10 + (xx%10);
    feat[(size_t)row * 128 + c] = f2bf(v);
    float sq = v * v;
    #pragma unroll
    for (int off = 32; off; off >>= 1) sq += __shfl_down(sq, off);
    __shared__ float red[4];
    if ((t & 63) == 0) red[t >> 6] = sq;
    __syncthreads();
    if (t == s * 128) {
        float totn = red[s*2] + red[s*2+1];
        atomicMax(maxn, __float_as_uint(totn));
    }
}

// ---------------- contrastive: MFMA streaming fixed-bound softmax GEMM ----------------
// grid (8 j-splits, 64 patches) x 256. Wave w owns anchor M-tiles {w, w+4}; A-frags in regs.
__global__ __launch_bounds__(256) void contrast_mfma(
    const u16* __restrict__ feat, const int* __restrict__ lab,
    const unsigned int* __restrict__ maxn, float* __restrict__ partials)
{
    int js = blockIdx.x;      // 0..7
    int p  = blockIdx.y;      // 0..63
    int t = threadIdx.x, lane = t & 63, wv = t >> 6;
    int idx15 = lane & 15;    // A-row / B-col / D-col within tile
    int kg = lane >> 4;       // k-group

    float M = 2.f * sqrtf(__uint_as_float(*maxn)) + 4.f;  // logit upper bound
    float M2 = M * 1.44269504f;

    // A fragments (anchors) held in registers; pad rows >= 100 are zero
    bf16x8 A[2][4];
    bf16x8 zz = {0,0,0,0,0,0,0,0};
    #pragma unroll
    for (int mi = 0; mi < 2; ++mi) {
        int m = wv + mi*4;
        #pragma unroll
        for (int c = 0; c < 4; ++c) {
            int a = 16*m + idx15;
            A[mi][c] = (m < 7 && a < 100)
                ? *(const bf16x8*)&feat[(size_t)(p*100 + a)*128 + c*32 + kg*8]
                : zz;
        }
    }
    // per-lane anchor labels (bit i=mi*4+r set iff label==1)
    unsigned int labmask = 0;
    #pragma unroll
    for (int mi = 0; mi < 2; ++mi) {
        int m = wv + mi*4;
        if (m < 7) {
            #pragma unroll
            for (int r = 0; r < 4; ++r) {
                int a = 16*m + 4*kg + r;
                int la = (a < 100) ? lab[p*100 + a] : 0;
                labmask |= (unsigned int)(la & 1) << (mi*4 + r);
            }
        }
    }

    int jbase = js * 1600;
    float sE[8] = {}, sP[8] = {}, sC[8] = {};

    for (int jt = 0; jt < 100; ++jt) {
        int jrow = jbase + jt*16;
        bf16x8 B[4];
        #pragma unroll
        for (int c = 0; c < 4; ++c)
            B[c] = *(const bf16x8*)&feat[(size_t)(jrow + idx15)*128 + c*32 + kg*8];
        int lj = lab[jrow + idx15];
        unsigned int mm = lj ? labmask : ~labmask;
        #pragma unroll
        for (int mi = 0; mi < 2; ++mi) {
            int m = wv + mi*4;
            if (m < 7) {
                f32x4 C = {0.f, 0.f, 0.f, 0.f};
                #pragma unroll
                for (int c = 0; c < 4; ++c)
                    C = __builtin_amdgcn_mfma_f32_16x16x32_bf16(A[mi][c], B[c], C, 0, 0, 0);
                #pragma unroll
                for (int r = 0; r < 4; ++r) {
                    float dot = C[r];
                    float e = exp2f(dot * 2.885390082f - M2);   // exp(2*dot - M)
                    int i = mi*4 + r;
                    sE[i] += e;
                    if ((mm >> i) & 1) { sP[i] += dot; sC[i] += 1.f; }
                }
            }
        }
    }

    // reduce across the 16 j-columns (lanes sharing kg), write partials
    #pragma unroll
    for (int mi = 0; mi < 2; ++mi) {
        int m = wv + mi*4;
        if (m < 7) {
            #pragma unroll
            for (int r = 0; r < 4; ++r) {
                int i = mi*4 + r;
                float s = sE[i], qq = sP[i], cc = sC[i];
                #pragma unroll
                for (int off = 1; off < 16; off <<= 1) {
                    s  += __shfl_xor(s,  off);
                    qq += __shfl_xor(qq, off);
                    cc += __shfl_xor(cc, off);
                }
                if (idx15 == 0) {
                    int a = 16*m + 4*kg + r;
                    float* dst = &partials[(((size_t)p*8 + js)*112 + a)*3];
                    dst[0] = s; dst[1] = qq; dst[2] = cc;
                }
            }
        }
    }
}

// ---------------- merge contrastive partials ----------------
__global__ __launch_bounds__(128) void merge_contrast(
    const float* __restrict__ partials, const float* __restrict__ fc_cnt,
    const unsigned int* __restrict__ maxn, float* __restrict__ acc)
{
    int p = blockIdx.x, t = threadIdx.x;
    float pa = 0.f;
    if (t < 100) {
        float s = 0.f, Sp = 0.f, cn = 0.f;
        for (int js = 0; js < 8; ++js) {
            const float* src = &partials[(((size_t)p*8 + js)*112 + t)*3];
            s += src[0]; Sp += src[1]; cn += src[2];
        }
        float M = 2.f * sqrtf(__uint_as_float(*maxn)) + 4.f;
        float lse = M + logf(s);
        pa = lse - 2.f * Sp / fmaxf(cn, 1.f);
    }
    #pragma unroll
    for (int off = 32; off; off >>= 1) pa += __shfl_down(pa, off);
    __shared__ float w2[2];
    if ((t & 63) == 0) w2[t >> 6] = pa;
    __syncthreads();
    if (t == 0) {
        float loss_p = (w2[0] + w2[1]) / 100.f;
        float fcv = fc_cnt[p] / 100.f;
        float inc = ((fcv > 0.1f) && (fcv < 0.9f)) ? 0.f : 1.f;
        atomicAdd(&acc[5], loss_p * inc);
        atomicAdd(&acc[6], inc);
    }
}

// ---------------- final combine ----------------
__global__ void final_kernel(const float* __restrict__ acc,
                             const int* __restrict__ epoch_p,
                             float* __restrict__ out)
{
    if (threadIdx.x == 0 && blockIdx.x == 0) {
        float loss_sup = acc[0] / fmaxf(acc[1], 1.f);
        int epoch = *epoch_p;
        float loss = loss_sup;
        if (epoch >= 5) {
            float contr = acc[5] / fmaxf(acc[6], 1.f);
            float cons  = acc[3] / fmaxf(acc[4], 1.f);
            float ent   = acc[2] / 6400.f;
            float ramp  = fminf(fmaxf((float)epoch / 40.f, 0.f), 1.f);
            float d = 1.f - ramp;
            float cons_w = expf(-5.f * d * d);
            loss = loss_sup + 0.1f * contr + cons_w * cons + 0.01f * ent;
        }
        out[0] = loss;
    }
}

extern "C" void kernel_launch(void* const* d_in, const int* in_sizes, int n_in,
                              void* d_out, int out_size, void* d_ws, size_t ws_size,
                              hipStream_t stream)
{
    const float* x_l      = (const float*)d_in[0];
    const int*   y_l      = (const int*)  d_in[1];
    const float* x_ul     = (const float*)d_in[2];
    const int*   epoch    = (const int*)  d_in[3];
    const float* proj_ema = (const float*)d_in[4];
    const float* z_ema    = (const float*)d_in[5];
    const float* W1       = (const float*)d_in[6];
    const float* W2       = (const float*)d_in[7];
    const float* W3       = (const float*)d_in[8];
    const float* Wc       = (const float*)d_in[9];
    const float* bc       = (const float*)d_in[10];
    const float* Wp       = (const float*)d_in[11];
    float* out = (float*)d_out;
    float* ws  = (float*)d_ws;

    float* fea1   = ws + WS_FEA1;
    float* fea2   = ws + WS_FEA2;
    float* fea3l  = ws + WS_FEA3L;
    float* fea3u  = ws + WS_FEA3U;
    float* zls    = ws + WS_ZLS;
    float* zul    = ws + WS_ZUL;
    u16*   featB  = (u16*)(ws + WS_FEATB);
    int*   labA   = (int*)(ws + WS_LAB);
    float* part   = ws + WS_PART;
    float* acc    = ws + WS_ACC;
    float* fc     = ws + WS_FC;
    unsigned int* maxn = (unsigned int*)(acc + 7);

    // zero accumulators + per-patch counts (+maxnorm at acc[7]) each call
    hipMemsetAsync(acc, 0, (16 + 64) * sizeof(float), stream);

    // ---- labeled branch ----
    conv3x3_s2_relu_t<<<dim3(25, 16, 4), 256, 0, stream>>>(x_l, W1, fea1, 3, 320, 320, 64);
    conv3x3_s2_relu_t<<<dim3(7, 32, 4), 256, 0, stream>>>(fea1, W2, fea2, 64, 160, 160, 128);
    conv3x3_s2_relu_t<<<dim3(2, 64, 4), 256, 0, stream>>>(fea2, W3, fea3l, 128, 80, 80, 256);
    conv1x1_cls<<<25, 256, 0, stream>>>(fea3l, Wc, bc, zls);
    loss_sup_kernel<<<1600, 256, 0, stream>>>(zls, y_l, acc);

    // ---- unlabeled branch ----
    conv3x3_s2_relu_t<<<dim3(25, 16, 4), 256, 0, stream>>>(x_ul, W1, fea1, 3, 320, 320, 64);
    conv3x3_s2_relu_t<<<dim3(7, 32, 4), 256, 0, stream>>>(fea1, W2, fea2, 64, 160, 160, 128);
    conv3x3_s2_relu_t<<<dim3(2, 64, 4), 256, 0, stream>>>(fea2, W3, fea3u, 128, 80, 80, 256);
    conv1x1_cls<<<25, 256, 0, stream>>>(fea3u, Wc, bc, zul);

    proj_gemm<<<dim3(25, 4), 256, 0, stream>>>(fea3u, Wp, featB);
    ema_scatter<<<3200, 256, 0, stream>>>(proj_ema, featB, maxn);
    ul_small_kernel<<<25, 256, 0, stream>>>(zul, z_ema, labA, acc, fc);

    contrast_mfma<<<dim3(8, 64), 256, 0, stream>>>(featB, labA, maxn, part);
    merge_contrast<<<64, 128, 0, stream>>>(part, fc, maxn, acc);
    final_kernel<<<1, 64, 0, stream>>>(acc, epoch, out);
}

// Round 3
// 691.543 us; speedup vs baseline: 5.5777x; 1.6870x over previous
//
#include <hip/hip_runtime.h>
#include <math.h>

typedef unsigned short u16;
typedef __attribute__((ext_vector_type(8))) short bf16x8;
typedef __attribute__((ext_vector_type(4))) float f32x4;

// ---------------- workspace layout (float-element offsets) ----------------
static const size_t WS_FEA1B = 0;          // 4*64*160*160 bf16 -> 3,276,800 slots
static const size_t WS_FEA2B = 3276800;    // 4*128*80*80 bf16  -> 1,638,400 slots
static const size_t WS_FEA3L = 4915200;    // 4*256*40*40 fp32  -> 1,638,400
static const size_t WS_FEA3U = 6553600;    // 1,638,400
static const size_t WS_ZLS   = 8192000;    // 12,800
static const size_t WS_ZUL   = 8204800;    // 12,800
static const size_t WS_FEATB = 8217600;    // 12800*128 bf16 -> 819,200 slots
static const size_t WS_LAB   = 9036800;    // 12,800 int
static const size_t WS_PART  = 9049600;    // 64*8*112*3 = 172,032
static const size_t WS_ACC   = 9221632;    // 16 floats (acc[7] = maxnorm2 bits)
static const size_t WS_FC    = 9221648;    // 64 floats
static const size_t WS_WT2   = 9221712;    // 9*128*64 bf16 -> 36,864 slots
static const size_t WS_WT3   = 9258576;    // 9*256*128 bf16 -> 147,456 slots
// end 9,406,032 floats = 37.6 MB

__device__ inline u16 f2bf(float x) {
    unsigned int u = __float_as_uint(x);
    unsigned int r = u + 0x7fffu + ((u >> 16) & 1u);
    return (u16)(r >> 16);
}

// ---------------- weight transform: W[co][ci][3][3] fp32 -> Wt[tap][co][ci] bf16 ----------------
__global__ __launch_bounds__(256) void wtrans(
    const float* __restrict__ W2, const float* __restrict__ W3,
    u16* __restrict__ wt2, u16* __restrict__ wt3)
{
    int tid = blockIdx.x * 256 + threadIdx.x;
    if (tid < 73728) {               // W2: Co=128, Ci=64
        int ci = tid & 63, rest = tid >> 6;
        int co = rest & 127, tap = rest >> 7;
        wt2[tid] = f2bf(W2[((size_t)co*64 + ci)*9 + tap]);
    } else {                         // W3: Co=256, Ci=128
        int t3 = tid - 73728;        // < 294912
        int ci = t3 & 127, rest = t3 >> 7;
        int co = rest & 255, tap = rest >> 8;
        wt3[t3] = f2bf(W3[((size_t)co*128 + ci)*9 + tap]);
    }
}

// ---------------- conv1: 3->64, 320->160, fp32 compute, bf16 out ----------------
// block = (oy, n); 256 threads: co = t&63, g = t>>6 owns ox [g*40, g*40+40)
__global__ __launch_bounds__(256) void conv1_k(
    const float* __restrict__ x, const float* __restrict__ W1,
    u16* __restrict__ fea1b)
{
    int oy = blockIdx.x;
    int n  = blockIdx.y;
    int t = threadIdx.x;
    int co = t & 63, g = t >> 6;
    __shared__ float lds[9*324];
    for (int u = t; u < 9*322; u += 256) {
        int plane = u / 322, col = u - plane*322;
        int ci = plane / 3, ky = plane - ci*3;
        int iy = oy*2 + ky;
        float v = 0.f;
        if (iy < 320 && col < 320)
            v = x[(((size_t)n*3 + ci)*320 + iy)*320 + col];
        lds[plane*324 + col] = v;
    }
    __syncthreads();
    float w[27];
    #pragma unroll
    for (int k = 0; k < 27; ++k) w[k] = W1[co*27 + k];
    float acc[40];
    #pragma unroll
    for (int i = 0; i < 40; ++i) acc[i] = 0.f;
    #pragma unroll
    for (int ci = 0; ci < 3; ++ci) {
        #pragma unroll
        for (int ky = 0; ky < 3; ++ky) {
            const float* base = &lds[(ci*3+ky)*324 + g*80];
            const float* wk = &w[(ci*3+ky)*3];
            #pragma unroll
            for (int q = 0; q < 10; ++q) {
                float4 a = *(const float4*)&base[q*8];
                float4 b = *(const float4*)&base[q*8+4];
                float2 c = *(const float2*)&base[q*8+8];
                float xx[10] = {a.x,a.y,a.z,a.w,b.x,b.y,b.z,b.w,c.x,c.y};
                #pragma unroll
                for (int oo = 0; oo < 4; ++oo)
                    acc[q*4+oo] += wk[0]*xx[2*oo] + wk[1]*xx[2*oo+1] + wk[2]*xx[2*oo+2];
            }
        }
    }
    u16* dst = fea1b + (((size_t)n*64 + co)*160 + oy)*160 + g*40;
    #pragma unroll
    for (int i = 0; i < 20; ++i) {
        float v0 = fmaxf(acc[2*i], 0.f), v1 = fmaxf(acc[2*i+1], 0.f);
        ((unsigned int*)dst)[i] = (unsigned int)f2bf(v0) | ((unsigned int)f2bf(v1) << 16);
    }
}

// ---------------- implicit-GEMM MFMA conv 3x3 s2 (+ReLU) ----------------
// bf16 input [4][Ci][H][H], weights wt[tap][Co][Ci] bf16, output [4][Co][OH][OH].
// Block: 64 co x 64 opx (8x8). 4 waves; wave wv = m-tile of 16 co, 4 n-tiles each.
template<int Ci, int Co, int H, int OH, bool OB>
__global__ __launch_bounds__(256) void conv3x3_mfma(
    const u16* __restrict__ inb, const u16* __restrict__ wt,
    u16* __restrict__ outb, float* __restrict__ outf)
{
    constexpr int TILES = OH/8;
    int tile = blockIdx.x;
    int co0  = blockIdx.y * 64;
    int n    = blockIdx.z;
    int ty = tile / TILES, tx = tile - ty*TILES;
    int oy0 = ty*8, ox0 = tx*8;
    int iy0 = oy0*2, ix0 = ox0*2;
    int t = threadIdx.x, lane = t & 63, wv = t >> 6;
    int idx15 = lane & 15, kg = lane >> 4;

    __shared__ u16 lds[17*18*32];   // 19,584 B

    f32x4 acc[4];
    #pragma unroll
    for (int nt = 0; nt < 4; ++nt) acc[nt] = (f32x4){0.f,0.f,0.f,0.f};

    const u16* ibase = inb + (size_t)n * Ci * H * H;

    for (int c0 = 0; c0 < Ci; c0 += 32) {
        __syncthreads();   // prior-chunk reads done
        // stage 32 ci x 17 x 18 halo, ci-pairs packed as u32, slot-XOR swizzle
        for (int u = t; u < 16*17*18; u += 256) {
            int pr = u / 18, j = u - pr*18;
            int ci2 = pr / 17, iyl = pr - ci2*17;
            int ci_l = ci2*2;
            int iy = iy0 + iyl, ix = ix0 + j;
            unsigned int v = 0;
            if (iy < H && ix < H) {
                const u16* p = ibase + ((size_t)(c0+ci_l)*H + iy)*H + ix;
                v = (unsigned int)p[0] | ((unsigned int)p[(size_t)H*H] << 16);
            }
            int pix = iyl*18 + j;
            int sg = (ci_l >> 3) ^ ((pix >> 1) & 3);
            ((unsigned int*)lds)[(pix*32 + sg*8 + (ci_l & 7)) >> 1] = v;
        }
        __syncthreads();

        // prefetch the 9 A-fragments (this wave's co row, this ci chunk)
        bf16x8 A[9];
        const u16* wb = wt + (size_t)(co0 + wv*16 + idx15)*Ci + c0 + kg*8;
        #pragma unroll
        for (int tap = 0; tap < 9; ++tap)
            A[tap] = *(const bf16x8*)(wb + (size_t)tap*Co*Ci);

        #pragma unroll
        for (int tap = 0; tap < 9; ++tap) {
            int ky = tap/3, kx = tap - ky*3;
            #pragma unroll
            for (int nt = 0; nt < 4; ++nt) {
                int l = nt*16 + idx15;
                int pix = (2*(l>>3) + ky)*18 + 2*(l&7) + kx;
                int slot = kg ^ ((pix >> 1) & 3);
                bf16x8 B = *(const bf16x8*)&lds[pix*32 + slot*8];
                acc[nt] = __builtin_amdgcn_mfma_f32_16x16x32_bf16(A[tap], B, acc[nt], 0, 0, 0);
            }
        }
    }

    // epilogue: D row = kg*4 + r, col = idx15
    int co = co0 + wv*16 + kg*4;
    #pragma unroll
    for (int nt = 0; nt < 4; ++nt) {
        int l = nt*16 + idx15;
        int oy = oy0 + (l>>3), ox = ox0 + (l&7);
        #pragma unroll
        for (int r = 0; r < 4; ++r) {
            float v = fmaxf(acc[nt][r], 0.f);
            size_t o = (((size_t)n*Co + co + r)*OH + oy)*OH + ox;
            if (OB) outb[o] = f2bf(v); else outf[o] = v;
        }
    }
}

// ---------------- 1x1 classifier conv, ci-split with atomics (bias in consumers) ----------------
__global__ __launch_bounds__(256) void conv1x1_cls(
    const float* __restrict__ fea, const float* __restrict__ Wc,
    float* __restrict__ z)
{
    int idx = blockIdx.x * 256 + threadIdx.x;   // 6400 px
    int cc0 = blockIdx.y * 32;
    int n = idx / 1600, r = idx - n*1600;
    const float* f = fea + ((size_t)n*256 + cc0)*1600 + r;
    float a0 = 0.f, a1 = 0.f;
    #pragma unroll
    for (int ci = 0; ci < 32; ++ci) {
        float v = f[(size_t)ci*1600];
        a0 += v * Wc[cc0+ci];
        a1 += v * Wc[256+cc0+ci];
    }
    atomicAdd(&z[(size_t)n*3200 + r], a0);
    atomicAdd(&z[(size_t)n*3200 + 1600 + r], a1);
}

// ---------------- supervised CE over bilinear-upsampled logits ----------------
__global__ __launch_bounds__(256) void loss_sup_kernel(
    const float* __restrict__ zs, const int* __restrict__ y,
    const float* __restrict__ bc, float* __restrict__ acc)
{
    int idx = blockIdx.x * 256 + threadIdx.x;   // 409600
    int n  = idx / 102400;
    int r  = idx - n*102400;
    int oy = r / 320, ox = r - oy*320;
    const float step = 39.0f / 319.0f;
    float ty = (float)oy * step, tx = (float)ox * step;
    int y0 = (int)floorf(ty), x0 = (int)floorf(tx);
    int y1 = min(y0 + 1, 39), x1 = min(x0 + 1, 39);
    float wy = ty - (float)y0, wx = tx - (float)x0;
    const float* base = zs + (size_t)n * 3200;
    float z[2];
    #pragma unroll
    for (int c = 0; c < 2; ++c) {
        const float* pl = base + c * 1600;
        float v00 = pl[y0*40 + x0], v01 = pl[y0*40 + x1];
        float v10 = pl[y1*40 + x0], v11 = pl[y1*40 + x1];
        float top = v00 * (1.f - wx) + v01 * wx;
        float bot = v10 * (1.f - wx) + v11 * wx;
        z[c] = top * (1.f - wy) + bot * wy + bc[c];
    }
    int lab = y[idx];
    bool valid = (lab != 255);
    int sl = min(max(lab, 0), 1);
    float mz  = fmaxf(z[0], z[1]);
    float lse = mz + logf(expf(z[0]-mz) + expf(z[1]-mz));
    float nll = lse - z[sl];
    float vn = valid ? nll : 0.f;
    float vd = valid ? 1.f : 0.f;
    #pragma unroll
    for (int off = 32; off; off >>= 1) { vn += __shfl_down(vn, off); vd += __shfl_down(vd, off); }
    if ((threadIdx.x & 63) == 0) { atomicAdd(&acc[0], vn); atomicAdd(&acc[1], vd); }
}

// ---------------- unlabeled small losses + pseudo labels + patch counts ----------------
__global__ __launch_bounds__(256) void ul_small_kernel(
    const float* __restrict__ z_ul, const float* __restrict__ z_ema,
    const float* __restrict__ bc,
    int* __restrict__ lab_all, float* __restrict__ acc, float* __restrict__ fc_cnt)
{
    int idx = blockIdx.x * 256 + threadIdx.x;   // 6400
    int n = idx / 1600;
    int r = idx - n*1600;
    int yy = r / 40, xx = r - yy*40;
    float z0 = z_ul[(size_t)n*3200 + r] + bc[0];
    float z1 = z_ul[(size_t)n*3200 + 1600 + r] + bc[1];
    float m = fmaxf(z0, z1);
    float e0 = expf(z0 - m), e1 = expf(z1 - m);
    float lse = m + logf(e0 + e1);
    float lp0 = z0 - lse, lp1 = z1 - lse;
    float p0 = expf(lp0), p1 = expf(lp1);
    float ent = -(p0*lp0 + p1*lp1);
    int pl = (z1 > z0) ? 1 : 0;
    float ze0 = z_ema[(size_t)n*3200 + r], ze1 = z_ema[(size_t)n*3200 + 1600 + r];
    float me = fmaxf(ze0, ze1);
    float f0 = expf(ze0 - me), f1 = expf(ze1 - me);
    float maxp = 1.f / (f0 + f1);
    int ple = (ze1 > ze0) ? 1 : 0;
    bool mask = (maxp > 0.6f);
    float nll = lse - (ple ? z1 : z0);

    int pi = yy / 10, hi = yy % 10, pj = xx / 10, wi = xx % 10;
    int patch = (pi*4 + pj)*4 + n;
    int row = patch * 100 + hi*10 + wi;
    lab_all[row]        = pl;
    lab_all[6400 + row] = ple;
    atomicAdd(&fc_cnt[patch], (float)pl);

    float cn = mask ? nll : 0.f;
    float cd = mask ? 1.f : 0.f;
    #pragma unroll
    for (int off = 32; off; off >>= 1) {
        ent += __shfl_down(ent, off);
        cn  += __shfl_down(cn, off);
        cd  += __shfl_down(cd, off);
    }
    if ((threadIdx.x & 63) == 0) {
        atomicAdd(&acc[2], ent);
        atomicAdd(&acc[3], cn);
        atomicAdd(&acc[4], cd);
    }
}

// ---------------- projector GEMM: wave = 32 out-channels, lane = pixel ----------------
__global__ __launch_bounds__(256) void proj_gemm(
    const float* __restrict__ fea, const float* __restrict__ Wp,
    u16* __restrict__ feat)
{
    int n = blockIdx.y;
    int px0 = blockIdx.x * 64;
    int lane = threadIdx.x & 63;
    int wv = threadIdx.x >> 6;
    int ch0 = wv * 32;
    int px = px0 + lane;
    const float* f = fea + (size_t)n * 256 * 1600 + px;
    float acc[32] = {};
    for (int ci0 = 0; ci0 < 256; ci0 += 4) {
        float v0 = f[(size_t)(ci0+0)*1600];
        float v1 = f[(size_t)(ci0+1)*1600];
        float v2 = f[(size_t)(ci0+2)*1600];
        float v3 = f[(size_t)(ci0+3)*1600];
        #pragma unroll
        for (int c = 0; c < 32; ++c) {
            float4 wv4 = *(const float4*)&Wp[(size_t)(ch0 + c)*256 + ci0];
            acc[c] += v0*wv4.x + v1*wv4.y + v2*wv4.z + v3*wv4.w;
        }
    }
    float sq = 0.f;
    #pragma unroll
    for (int c = 0; c < 32; ++c) sq += acc[c]*acc[c];
    __shared__ float red[4][64];
    red[wv][lane] = sq;
    __syncthreads();
    float tot = red[0][lane] + red[1][lane] + red[2][lane] + red[3][lane];
    float scale = 1.f / fmaxf(sqrtf(tot), 1e-12f);
    int yy = px / 40, xx = px % 40;
    int row = ((yy/10*4 + xx/10)*4 + n)*100 + (yy%10)*10 + (xx%10);
    u16* dst = feat + (size_t)row * 128 + ch0;
    #pragma unroll
    for (int c2 = 0; c2 < 16; ++c2) {
        unsigned int pk = (unsigned int)f2bf(acc[2*c2]*scale)
                        | ((unsigned int)f2bf(acc[2*c2+1]*scale) << 16);
        *(unsigned int*)&dst[c2*2] = pk;
    }
}

// ---------------- EMA scatter -> bf16 feat + per-row norm max ----------------
__global__ __launch_bounds__(256) void ema_scatter(
    const float* __restrict__ ema, u16* __restrict__ feat,
    unsigned int* __restrict__ maxn)
{
    int t = threadIdx.x;
    int c = t & 127, s = t >> 7;
    int px = blockIdx.x * 2 + s;      // 0..6399
    int n = px / 1600, r = px % 1600;
    float v = ema[((size_t)n * 128 + c) * 1600 + r];
    int yy = r / 40, xx = r % 40;
    int row = 6400 + ((yy/10*4 + xx/10)*4 + n)*100 + (yy%10)*10 + (xx%10);
    feat[(size_t)row * 128 + c] = f2bf(v);
    float sq = v * v;
    #pragma unroll
    for (int off = 32; off; off >>= 1) sq += __shfl_down(sq, off);
    __shared__ float red[4];
    if ((t & 63) == 0) red[t >> 6] = sq;
    __syncthreads();
    if (t == s * 128) {
        float totn = red[s*2] + red[s*2+1];
        atomicMax(maxn, __float_as_uint(totn));
    }
}

// ---------------- contrastive: MFMA streaming fixed-bound softmax GEMM ----------------
__global__ __launch_bounds__(256) void contrast_mfma(
    const u16* __restrict__ feat, const int* __restrict__ lab,
    const unsigned int* __restrict__ maxn, float* __restrict__ partials)
{
    int js = blockIdx.x;      // 0..7
    int p  = blockIdx.y;      // 0..63
    int t = threadIdx.x, lane = t & 63, wv = t >> 6;
    int idx15 = lane & 15;
    int kg = lane >> 4;

    float M = 2.f * sqrtf(__uint_as_float(*maxn)) + 4.f;
    float M2 = M * 1.44269504f;

    bf16x8 A[2][4];
    bf16x8 zz = {0,0,0,0,0,0,0,0};
    #pragma unroll
    for (int mi = 0; mi < 2; ++mi) {
        int m = wv + mi*4;
        #pragma unroll
        for (int c = 0; c < 4; ++c) {
            int a = 16*m + idx15;
            A[mi][c] = (m < 7 && a < 100)
                ? *(const bf16x8*)&feat[(size_t)(p*100 + a)*128 + c*32 + kg*8]
                : zz;
        }
    }
    unsigned int labmask = 0;
    #pragma unroll
    for (int mi = 0; mi < 2; ++mi) {
        int m = wv + mi*4;
        if (m < 7) {
            #pragma unroll
            for (int r = 0; r < 4; ++r) {
                int a = 16*m + 4*kg + r;
                int la = (a < 100) ? lab[p*100 + a] : 0;
                labmask |= (unsigned int)(la & 1) << (mi*4 + r);
            }
        }
    }

    int jbase = js * 1600;
    float sE[8] = {}, sP[8] = {}, sC[8] = {};

    for (int jt = 0; jt < 100; ++jt) {
        int jrow = jbase + jt*16;
        bf16x8 B[4];
        #pragma unroll
        for (int c = 0; c < 4; ++c)
            B[c] = *(const bf16x8*)&feat[(size_t)(jrow + idx15)*128 + c*32 + kg*8];
        int lj = lab[jrow + idx15];
        unsigned int mm = lj ? labmask : ~labmask;
        #pragma unroll
        for (int mi = 0; mi < 2; ++mi) {
            int m = wv + mi*4;
            if (m < 7) {
                f32x4 C = {0.f, 0.f, 0.f, 0.f};
                #pragma unroll
                for (int c = 0; c < 4; ++c)
                    C = __builtin_amdgcn_mfma_f32_16x16x32_bf16(A[mi][c], B[c], C, 0, 0, 0);
                #pragma unroll
                for (int r = 0; r < 4; ++r) {
                    float dot = C[r];
                    float e = exp2f(dot * 2.885390082f - M2);
                    int i = mi*4 + r;
                    sE[i] += e;
                    if ((mm >> i) & 1) { sP[i] += dot; sC[i] += 1.f; }
                }
            }
        }
    }

    #pragma unroll
    for (int mi = 0; mi < 2; ++mi) {
        int m = wv + mi*4;
        if (m < 7) {
            #pragma unroll
            for (int r = 0; r < 4; ++r) {
                int i = mi*4 + r;
                float s = sE[i], qq = sP[i], cc = sC[i];
                #pragma unroll
                for (int off = 1; off < 16; off <<= 1) {
                    s  += __shfl_xor(s,  off);
                    qq += __shfl_xor(qq, off);
                    cc += __shfl_xor(cc, off);
                }
                if (idx15 == 0) {
                    int a = 16*m + 4*kg + r;
                    float* dst = &partials[(((size_t)p*8 + js)*112 + a)*3];
                    dst[0] = s; dst[1] = qq; dst[2] = cc;
                }
            }
        }
    }
}

// ---------------- merge contrastive partials ----------------
__global__ __launch_bounds__(128) void merge_contrast(
    const float* __restrict__ partials, const float* __restrict__ fc_cnt,
    const unsigned int* __restrict__ maxn, float* __restrict__ acc)
{
    int p = blockIdx.x, t = threadIdx.x;
    float pa = 0.f;
    if (t < 100) {
        float s = 0.f, Sp = 0.f, cn = 0.f;
        for (int js = 0; js < 8; ++js) {
            const float* src = &partials[(((size_t)p*8 + js)*112 + t)*3];
            s += src[0]; Sp += src[1]; cn += src[2];
        }
        float M = 2.f * sqrtf(__uint_as_float(*maxn)) + 4.f;
        float lse = M + logf(s);
        pa = lse - 2.f * Sp / fmaxf(cn, 1.f);
    }
    #pragma unroll
    for (int off = 32; off; off >>= 1) pa += __shfl_down(pa, off);
    __shared__ float w2[2];
    if ((t & 63) == 0) w2[t >> 6] = pa;
    __syncthreads();
    if (t == 0) {
        float loss_p = (w2[0] + w2[1]) / 100.f;
        float fcv = fc_cnt[p] / 100.f;
        float inc = ((fcv > 0.1f) && (fcv < 0.9f)) ? 0.f : 1.f;
        atomicAdd(&acc[5], loss_p * inc);
        atomicAdd(&acc[6], inc);
    }
}

// ---------------- final combine ----------------
__global__ void final_kernel(const float* __restrict__ acc,
                             const int* __restrict__ epoch_p,
                             float* __restrict__ out)
{
    if (threadIdx.x == 0 && blockIdx.x == 0) {
        float loss_sup = acc[0] / fmaxf(acc[1], 1.f);
        int epoch = *epoch_p;
        float loss = loss_sup;
        if (epoch >= 5) {
            float contr = acc[5] / fmaxf(acc[6], 1.f);
            float cons  = acc[3] / fmaxf(acc[4], 1.f);
            float ent   = acc[2] / 6400.f;
            float ramp  = fminf(fmaxf((float)epoch / 40.f, 0.f), 1.f);
            float d = 1.f - ramp;
            float cons_w = expf(-5.f * d * d);
            loss = loss_sup + 0.1f * contr + cons_w * cons + 0.01f * ent;
        }
        out[0] = loss;
    }
}

extern "C" void kernel_launch(void* const* d_in, const int* in_sizes, int n_in,
                              void* d_out, int out_size, void* d_ws, size_t ws_size,
                              hipStream_t stream)
{
    const float* x_l      = (const float*)d_in[0];
    const int*   y_l      = (const int*)  d_in[1];
    const float* x_ul     = (const float*)d_in[2];
    const int*   epoch    = (const int*)  d_in[3];
    const float* proj_ema = (const float*)d_in[4];
    const float* z_ema    = (const float*)d_in[5];
    const float* W1       = (const float*)d_in[6];
    const float* W2       = (const float*)d_in[7];
    const float* W3       = (const float*)d_in[8];
    const float* Wc       = (const float*)d_in[9];
    const float* bc       = (const float*)d_in[10];
    const float* Wp       = (const float*)d_in[11];
    float* out = (float*)d_out;
    float* ws  = (float*)d_ws;

    u16*   fea1b = (u16*)(ws + WS_FEA1B);
    u16*   fea2b = (u16*)(ws + WS_FEA2B);
    float* fea3l = ws + WS_FEA3L;
    float* fea3u = ws + WS_FEA3U;
    float* zls   = ws + WS_ZLS;
    float* zul   = ws + WS_ZUL;
    u16*   featB = (u16*)(ws + WS_FEATB);
    int*   labA  = (int*)(ws + WS_LAB);
    float* part  = ws + WS_PART;
    float* acc   = ws + WS_ACC;
    float* fc    = ws + WS_FC;
    u16*   wt2   = (u16*)(ws + WS_WT2);
    u16*   wt3   = (u16*)(ws + WS_WT3);
    unsigned int* maxn = (unsigned int*)(acc + 7);

    // zero accumulators + fc + z buffers (z accumulated via atomics)
    hipMemsetAsync(acc, 0, (16 + 64) * sizeof(float), stream);
    hipMemsetAsync(zls, 0, 25600 * sizeof(float), stream);

    wtrans<<<1440, 256, 0, stream>>>(W2, W3, wt2, wt3);

    // ---- labeled branch ----
    conv1_k<<<dim3(160, 4), 256, 0, stream>>>(x_l, W1, fea1b);
    conv3x3_mfma<64,128,160,80,true><<<dim3(100, 2, 4), 256, 0, stream>>>(fea1b, wt2, fea2b, nullptr);
    conv3x3_mfma<128,256,80,40,false><<<dim3(25, 4, 4), 256, 0, stream>>>(fea2b, wt3, nullptr, fea3l);
    conv1x1_cls<<<dim3(25, 8), 256, 0, stream>>>(fea3l, Wc, zls);
    loss_sup_kernel<<<1600, 256, 0, stream>>>(zls, y_l, bc, acc);

    // ---- unlabeled branch ----
    conv1_k<<<dim3(160, 4), 256, 0, stream>>>(x_ul, W1, fea1b);
    conv3x3_mfma<64,128,160,80,true><<<dim3(100, 2, 4), 256, 0, stream>>>(fea1b, wt2, fea2b, nullptr);
    conv3x3_mfma<128,256,80,40,false><<<dim3(25, 4, 4), 256, 0, stream>>>(fea2b, wt3, nullptr, fea3u);
    conv1x1_cls<<<dim3(25, 8), 256, 0, stream>>>(fea3u, Wc, zul);

    proj_gemm<<<dim3(25, 4), 256, 0, stream>>>(fea3u, Wp, featB);
    ema_scatter<<<3200, 256, 0, stream>>>(proj_ema, featB, maxn);
    ul_small_kernel<<<25, 256, 0, stream>>>(zul, z_ema, bc, labA, acc, fc);

    contrast_mfma<<<dim3(8, 64), 256, 0, stream>>>(featB, labA, maxn, part);
    merge_contrast<<<64, 128, 0, stream>>>(part, fc, maxn, acc);
    final_kernel<<<1, 64, 0, stream>>>(acc, epoch, out);
}

// Round 4
// 463.605 us; speedup vs baseline: 8.3201x; 1.4917x over previous
//
#include <hip/hip_runtime.h>
#include <math.h>

typedef unsigned short u16;
typedef __attribute__((ext_vector_type(8))) short bf16x8;
typedef __attribute__((ext_vector_type(4))) float f32x4;

// ---------------- workspace layout (float-element offsets) ----------------
static const size_t WS_FEA1B = 0;          // 4*64*160*160 bf16 -> 3,276,800 slots
static const size_t WS_FEA2B = 3276800;    // 4*128*80*80 bf16  -> 1,638,400 slots
static const size_t WS_FEA3L = 4915200;    // 4*256*40*40 fp32  -> 1,638,400
static const size_t WS_FEA3U = 6553600;    // 1,638,400
static const size_t WS_ZLS   = 8192000;    // 12,800
static const size_t WS_ZUL   = 8204800;    // 12,800
static const size_t WS_FEATB = 8217600;    // 12800*128 bf16 -> 819,200 slots
static const size_t WS_LAB   = 9036800;    // 12,800 int
static const size_t WS_PART  = 9049600;    // 64*8*112*3 = 172,032
static const size_t WS_ACC   = 9221632;    // 16 floats (acc[7] = maxnorm2 bits)
static const size_t WS_FC    = 9221648;    // 64 floats
static const size_t WS_WT2   = 9221712;    // 9*128*64 bf16 -> 36,864 slots
static const size_t WS_WT3   = 9258576;    // 9*256*128 bf16 -> 147,456 slots
// end 9,406,032 floats = 37.6 MB

__device__ inline u16 f2bf(float x) {
    unsigned int u = __float_as_uint(x);
    unsigned int r = u + 0x7fffu + ((u >> 16) & 1u);
    return (u16)(r >> 16);
}

// ---------------- weight transform: W[co][ci][3][3] fp32 -> Wt[tap][co][ci] bf16 ----------------
__global__ __launch_bounds__(256) void wtrans(
    const float* __restrict__ W2, const float* __restrict__ W3,
    u16* __restrict__ wt2, u16* __restrict__ wt3)
{
    int tid = blockIdx.x * 256 + threadIdx.x;
    if (tid < 73728) {               // W2: Co=128, Ci=64
        int ci = tid & 63, rest = tid >> 6;
        int co = rest & 127, tap = rest >> 7;
        wt2[tid] = f2bf(W2[((size_t)co*64 + ci)*9 + tap]);
    } else {                         // W3: Co=256, Ci=128
        int t3 = tid - 73728;        // < 294912
        int ci = t3 & 127, rest = t3 >> 7;
        int co = rest & 255, tap = rest >> 8;
        wt3[t3] = f2bf(W3[((size_t)co*128 + ci)*9 + tap]);
    }
}

// ---------------- conv1: 3->64, 320->160, fp32 compute, bf16 out ----------------
__global__ __launch_bounds__(256) void conv1_k(
    const float* __restrict__ x, const float* __restrict__ W1,
    u16* __restrict__ fea1b)
{
    int oy = blockIdx.x;
    int n  = blockIdx.y;
    int t = threadIdx.x;
    int co = t & 63, g = t >> 6;
    __shared__ float lds[9*324];
    for (int u = t; u < 9*322; u += 256) {
        int plane = u / 322, col = u - plane*322;
        int ci = plane / 3, ky = plane - ci*3;
        int iy = oy*2 + ky;
        float v = 0.f;
        if (iy < 320 && col < 320)
            v = x[(((size_t)n*3 + ci)*320 + iy)*320 + col];
        lds[plane*324 + col] = v;
    }
    __syncthreads();
    float w[27];
    #pragma unroll
    for (int k = 0; k < 27; ++k) w[k] = W1[co*27 + k];
    float acc[40];
    #pragma unroll
    for (int i = 0; i < 40; ++i) acc[i] = 0.f;
    #pragma unroll
    for (int ci = 0; ci < 3; ++ci) {
        #pragma unroll
        for (int ky = 0; ky < 3; ++ky) {
            const float* base = &lds[(ci*3+ky)*324 + g*80];
            const float* wk = &w[(ci*3+ky)*3];
            #pragma unroll
            for (int q = 0; q < 10; ++q) {
                float4 a = *(const float4*)&base[q*8];
                float4 b = *(const float4*)&base[q*8+4];
                float2 c = *(const float2*)&base[q*8+8];
                float xx[10] = {a.x,a.y,a.z,a.w,b.x,b.y,b.z,b.w,c.x,c.y};
                #pragma unroll
                for (int oo = 0; oo < 4; ++oo)
                    acc[q*4+oo] += wk[0]*xx[2*oo] + wk[1]*xx[2*oo+1] + wk[2]*xx[2*oo+2];
            }
        }
    }
    u16* dst = fea1b + (((size_t)n*64 + co)*160 + oy)*160 + g*40;
    #pragma unroll
    for (int i = 0; i < 20; ++i) {
        float v0 = fmaxf(acc[2*i], 0.f), v1 = fmaxf(acc[2*i+1], 0.f);
        ((unsigned int*)dst)[i] = (unsigned int)f2bf(v0) | ((unsigned int)f2bf(v1) << 16);
    }
}

// ---------------- implicit-GEMM MFMA conv 3x3 s2 (+ReLU) ----------------
template<int Ci, int Co, int H, int OH, bool OB>
__global__ __launch_bounds__(256) void conv3x3_mfma(
    const u16* __restrict__ inb, const u16* __restrict__ wt,
    u16* __restrict__ outb, float* __restrict__ outf)
{
    constexpr int TILES = OH/8;
    int tile = blockIdx.x;
    int co0  = blockIdx.y * 64;
    int n    = blockIdx.z;
    int ty = tile / TILES, tx = tile - ty*TILES;
    int oy0 = ty*8, ox0 = tx*8;
    int iy0 = oy0*2, ix0 = ox0*2;
    int t = threadIdx.x, lane = t & 63, wv = t >> 6;
    int idx15 = lane & 15, kg = lane >> 4;

    __shared__ u16 lds[17*18*32];   // 19,584 B

    f32x4 acc[4];
    #pragma unroll
    for (int nt = 0; nt < 4; ++nt) acc[nt] = (f32x4){0.f,0.f,0.f,0.f};

    const u16* ibase = inb + (size_t)n * Ci * H * H;

    for (int c0 = 0; c0 < Ci; c0 += 32) {
        __syncthreads();
        for (int u = t; u < 16*17*18; u += 256) {
            int pr = u / 18, j = u - pr*18;
            int ci2 = pr / 17, iyl = pr - ci2*17;
            int ci_l = ci2*2;
            int iy = iy0 + iyl, ix = ix0 + j;
            unsigned int v = 0;
            if (iy < H && ix < H) {
                const u16* p = ibase + ((size_t)(c0+ci_l)*H + iy)*H + ix;
                v = (unsigned int)p[0] | ((unsigned int)p[(size_t)H*H] << 16);
            }
            int pix = iyl*18 + j;
            int sg = (ci_l >> 3) ^ ((pix >> 1) & 3);
            ((unsigned int*)lds)[(pix*32 + sg*8 + (ci_l & 7)) >> 1] = v;
        }
        __syncthreads();

        bf16x8 A[9];
        const u16* wb = wt + (size_t)(co0 + wv*16 + idx15)*Ci + c0 + kg*8;
        #pragma unroll
        for (int tap = 0; tap < 9; ++tap)
            A[tap] = *(const bf16x8*)(wb + (size_t)tap*Co*Ci);

        #pragma unroll
        for (int tap = 0; tap < 9; ++tap) {
            int ky = tap/3, kx = tap - ky*3;
            #pragma unroll
            for (int nt = 0; nt < 4; ++nt) {
                int l = nt*16 + idx15;
                int pix = (2*(l>>3) + ky)*18 + 2*(l&7) + kx;
                int slot = kg ^ ((pix >> 1) & 3);
                bf16x8 B = *(const bf16x8*)&lds[pix*32 + slot*8];
                acc[nt] = __builtin_amdgcn_mfma_f32_16x16x32_bf16(A[tap], B, acc[nt], 0, 0, 0);
            }
        }
    }

    int co = co0 + wv*16 + kg*4;
    #pragma unroll
    for (int nt = 0; nt < 4; ++nt) {
        int l = nt*16 + idx15;
        int oy = oy0 + (l>>3), ox = ox0 + (l&8? 8:0) + (l&7);
        ox = ox0 + (l&7);
        #pragma unroll
        for (int r = 0; r < 4; ++r) {
            float v = fmaxf(acc[nt][r], 0.f);
            size_t o = (((size_t)n*Co + co + r)*OH + oy)*OH + ox;
            if (OB) outb[o] = f2bf(v); else outf[o] = v;
        }
    }
}

// ---------------- 1x1 classifier conv, ci-split with atomics (bias in consumers) ----------------
__global__ __launch_bounds__(256) void conv1x1_cls(
    const float* __restrict__ fea, const float* __restrict__ Wc,
    float* __restrict__ z)
{
    int idx = blockIdx.x * 256 + threadIdx.x;   // 6400 px
    int cc0 = blockIdx.y * 32;
    int n = idx / 1600, r = idx - n*1600;
    const float* f = fea + ((size_t)n*256 + cc0)*1600 + r;
    float a0 = 0.f, a1 = 0.f;
    #pragma unroll
    for (int ci = 0; ci < 32; ++ci) {
        float v = f[(size_t)ci*1600];
        a0 += v * Wc[cc0+ci];
        a1 += v * Wc[256+cc0+ci];
    }
    atomicAdd(&z[(size_t)n*3200 + r], a0);
    atomicAdd(&z[(size_t)n*3200 + 1600 + r], a1);
}

// ---------------- supervised CE: grid-stride + block reduce (2 atomics/block) ----------------
__global__ __launch_bounds__(256) void loss_sup_kernel(
    const float* __restrict__ zs, const int* __restrict__ y,
    const float* __restrict__ bc, float* __restrict__ acc)
{
    const float step = 39.0f / 319.0f;
    float b0 = bc[0], b1 = bc[1];
    float vn = 0.f, vd = 0.f;
    for (int idx = blockIdx.x*256 + threadIdx.x; idx < 409600; idx += gridDim.x*256) {
        int n  = idx / 102400;
        int r  = idx - n*102400;
        int oy = r / 320, ox = r - oy*320;
        float ty = (float)oy * step, tx = (float)ox * step;
        int y0 = (int)ty, x0 = (int)tx;
        int y1 = min(y0 + 1, 39), x1 = min(x0 + 1, 39);
        float wy = ty - (float)y0, wx = tx - (float)x0;
        const float* base = zs + (size_t)n * 3200;
        float z[2];
        #pragma unroll
        for (int c = 0; c < 2; ++c) {
            const float* pl = base + c * 1600;
            float v00 = pl[y0*40 + x0], v01 = pl[y0*40 + x1];
            float v10 = pl[y1*40 + x0], v11 = pl[y1*40 + x1];
            float top = v00 * (1.f - wx) + v01 * wx;
            float bot = v10 * (1.f - wx) + v11 * wx;
            z[c] = top * (1.f - wy) + bot * wy + (c ? b1 : b0);
        }
        int lab = y[idx];
        bool valid = (lab != 255);
        int sl = min(max(lab, 0), 1);
        float mz  = fmaxf(z[0], z[1]);
        float lse = mz + logf(expf(z[0]-mz) + expf(z[1]-mz));
        float nll = lse - z[sl];
        if (valid) { vn += nll; vd += 1.f; }
    }
    #pragma unroll
    for (int off = 32; off; off >>= 1) { vn += __shfl_down(vn, off); vd += __shfl_down(vd, off); }
    __shared__ float rb[8];
    int wv = threadIdx.x >> 6;
    if ((threadIdx.x & 63) == 0) { rb[wv*2] = vn; rb[wv*2+1] = vd; }
    __syncthreads();
    if (threadIdx.x == 0) {
        atomicAdd(&acc[0], rb[0]+rb[2]+rb[4]+rb[6]);
        atomicAdd(&acc[1], rb[1]+rb[3]+rb[5]+rb[7]);
    }
}

// ---------------- unlabeled small losses + pseudo labels + patch counts ----------------
__global__ __launch_bounds__(256) void ul_small_kernel(
    const float* __restrict__ z_ul, const float* __restrict__ z_ema,
    const float* __restrict__ bc,
    int* __restrict__ lab_all, float* __restrict__ acc, float* __restrict__ fc_cnt)
{
    int idx = blockIdx.x * 256 + threadIdx.x;   // 6400
    int n = idx / 1600;
    int r = idx - n*1600;
    int yy = r / 40, xx = r - yy*40;
    float z0 = z_ul[(size_t)n*3200 + r] + bc[0];
    float z1 = z_ul[(size_t)n*3200 + 1600 + r] + bc[1];
    float m = fmaxf(z0, z1);
    float e0 = expf(z0 - m), e1 = expf(z1 - m);
    float lse = m + logf(e0 + e1);
    float lp0 = z0 - lse, lp1 = z1 - lse;
    float p0 = expf(lp0), p1 = expf(lp1);
    float ent = -(p0*lp0 + p1*lp1);
    int pl = (z1 > z0) ? 1 : 0;
    float ze0 = z_ema[(size_t)n*3200 + r], ze1 = z_ema[(size_t)n*3200 + 1600 + r];
    float me = fmaxf(ze0, ze1);
    float f0 = expf(ze0 - me), f1 = expf(ze1 - me);
    float maxp = 1.f / (f0 + f1);
    int ple = (ze1 > ze0) ? 1 : 0;
    bool mask = (maxp > 0.6f);
    float nll = lse - (ple ? z1 : z0);

    int pi = yy / 10, hi = yy % 10, pj = xx / 10, wi = xx % 10;
    int patch = (pi*4 + pj)*4 + n;
    int row = patch * 100 + hi*10 + wi;
    lab_all[row]        = pl;
    lab_all[6400 + row] = ple;
    atomicAdd(&fc_cnt[patch], (float)pl);

    float cn = mask ? nll : 0.f;
    float cd = mask ? 1.f : 0.f;
    #pragma unroll
    for (int off = 32; off; off >>= 1) {
        ent += __shfl_down(ent, off);
        cn  += __shfl_down(cn, off);
        cd  += __shfl_down(cd, off);
    }
    if ((threadIdx.x & 63) == 0) {
        atomicAdd(&acc[2], ent);
        atomicAdd(&acc[3], cn);
        atomicAdd(&acc[4], cd);
    }
}

// ---------------- projector GEMM: wave = 32 out-channels, lane = pixel ----------------
__global__ __launch_bounds__(256) void proj_gemm(
    const float* __restrict__ fea, const float* __restrict__ Wp,
    u16* __restrict__ feat)
{
    int n = blockIdx.y;
    int px0 = blockIdx.x * 64;
    int lane = threadIdx.x & 63;
    int wv = threadIdx.x >> 6;
    int ch0 = wv * 32;
    int px = px0 + lane;
    const float* f = fea + (size_t)n * 256 * 1600 + px;
    float acc[32] = {};
    for (int ci0 = 0; ci0 < 256; ci0 += 4) {
        float v0 = f[(size_t)(ci0+0)*1600];
        float v1 = f[(size_t)(ci0+1)*1600];
        float v2 = f[(size_t)(ci0+2)*1600];
        float v3 = f[(size_t)(ci0+3)*1600];
        #pragma unroll
        for (int c = 0; c < 32; ++c) {
            float4 wv4 = *(const float4*)&Wp[(size_t)(ch0 + c)*256 + ci0];
            acc[c] += v0*wv4.x + v1*wv4.y + v2*wv4.z + v3*wv4.w;
        }
    }
    float sq = 0.f;
    #pragma unroll
    for (int c = 0; c < 32; ++c) sq += acc[c]*acc[c];
    __shared__ float red[4][64];
    red[wv][lane] = sq;
    __syncthreads();
    float tot = red[0][lane] + red[1][lane] + red[2][lane] + red[3][lane];
    float scale = 1.f / fmaxf(sqrtf(tot), 1e-12f);
    int yy = px / 40, xx = px % 40;
    int row = ((yy/10*4 + xx/10)*4 + n)*100 + (yy%10)*10 + (xx%10);
    u16* dst = feat + (size_t)row * 128 + ch0;
    #pragma unroll
    for (int c2 = 0; c2 < 16; ++c2) {
        unsigned int pk = (unsigned int)f2bf(acc[2*c2]*scale)
                        | ((unsigned int)f2bf(acc[2*c2+1]*scale) << 16);
        *(unsigned int*)&dst[c2*2] = pk;
    }
}

// ---------------- EMA scatter: coalesced tile-transpose + 1 atomicMax/block ----------------
// grid 100: block = 64-px tile of one image. Load lane->pixel (coalesced),
// XOR-swizzled LDS transpose, write 4 threads/px (4x16B stores).
__global__ __launch_bounds__(256) void ema_scatter(
    const float* __restrict__ ema, u16* __restrict__ feat,
    unsigned int* __restrict__ maxn)
{
    __shared__ float lds[128*64];    // 32 KB, col = pxl ^ ((c>>5)<<3)
    int b = blockIdx.x;              // 0..99
    int n = b / 25;
    int r0 = (b - n*25) * 64;
    int t = threadIdx.x, lane = t & 63, wv = t >> 6;

    const float* src = ema + ((size_t)n*128 + wv*32)*1600 + r0 + lane;
    int scol = lane ^ (wv << 3);
    #pragma unroll
    for (int cc = 0; cc < 32; ++cc)
        lds[(wv*32 + cc)*64 + scol] = src[(size_t)cc*1600];
    __syncthreads();

    int pxl = t >> 2, cq = t & 3;
    int r = r0 + pxl;
    int yy = r / 40, xx = r - yy*40;
    int row = 6400 + ((yy/10*4 + xx/10)*4 + n)*100 + (yy%10)*10 + (xx%10);
    int rcol = pxl ^ (cq << 3);
    float sq = 0.f;
    unsigned int pk[16];
    #pragma unroll
    for (int i = 0; i < 16; ++i) {
        float v0 = lds[(cq*32 + 2*i)*64 + rcol];
        float v1 = lds[(cq*32 + 2*i + 1)*64 + rcol];
        sq += v0*v0 + v1*v1;
        pk[i] = (unsigned int)f2bf(v0) | ((unsigned int)f2bf(v1) << 16);
    }
    u16* dst = feat + (size_t)row*128 + cq*32;
    #pragma unroll
    for (int i = 0; i < 4; ++i)
        *(uint4*)&((unsigned int*)dst)[i*4] = *(uint4*)&pk[i*4];

    sq += __shfl_xor(sq, 1);
    sq += __shfl_xor(sq, 2);         // full norm^2 at each of the 4 threads of the px
    float mx = sq;
    #pragma unroll
    for (int off = 4; off < 64; off <<= 1) mx = fmaxf(mx, __shfl_xor(mx, off));
    __shared__ float red[4];
    if (lane == 0) red[wv] = mx;
    __syncthreads();
    if (t == 0)
        atomicMax(maxn, __float_as_uint(fmaxf(fmaxf(red[0], red[1]),
                                              fmaxf(red[2], red[3]))));
}

// ---------------- contrastive: MFMA streaming fixed-bound softmax GEMM ----------------
__global__ __launch_bounds__(256) void contrast_mfma(
    const u16* __restrict__ feat, const int* __restrict__ lab,
    const unsigned int* __restrict__ maxn, float* __restrict__ partials)
{
    int js = blockIdx.x;      // 0..7
    int p  = blockIdx.y;      // 0..63
    int t = threadIdx.x, lane = t & 63, wv = t >> 6;
    int idx15 = lane & 15;
    int kg = lane >> 4;

    float M = 2.f * sqrtf(__uint_as_float(*maxn)) + 4.f;
    float M2 = M * 1.44269504f;

    bf16x8 A[2][4];
    bf16x8 zz = {0,0,0,0,0,0,0,0};
    #pragma unroll
    for (int mi = 0; mi < 2; ++mi) {
        int m = wv + mi*4;
        #pragma unroll
        for (int c = 0; c < 4; ++c) {
            int a = 16*m + idx15;
            A[mi][c] = (m < 7 && a < 100)
                ? *(const bf16x8*)&feat[(size_t)(p*100 + a)*128 + c*32 + kg*8]
                : zz;
        }
    }
    unsigned int labmask = 0;
    #pragma unroll
    for (int mi = 0; mi < 2; ++mi) {
        int m = wv + mi*4;
        if (m < 7) {
            #pragma unroll
            for (int r = 0; r < 4; ++r) {
                int a = 16*m + 4*kg + r;
                int la = (a < 100) ? lab[p*100 + a] : 0;
                labmask |= (unsigned int)(la & 1) << (mi*4 + r);
            }
        }
    }

    int jbase = js * 1600;
    float sE[8] = {}, sP[8] = {}, sC[8] = {};

    for (int jt = 0; jt < 100; ++jt) {
        int jrow = jbase + jt*16;
        bf16x8 B[4];
        #pragma unroll
        for (int c = 0; c < 4; ++c)
            B[c] = *(const bf16x8*)&feat[(size_t)(jrow + idx15)*128 + c*32 + kg*8];
        int lj = lab[jrow + idx15];
        unsigned int mm = lj ? labmask : ~labmask;
        #pragma unroll
        for (int mi = 0; mi < 2; ++mi) {
            int m = wv + mi*4;
            if (m < 7) {
                f32x4 C = {0.f, 0.f, 0.f, 0.f};
                #pragma unroll
                for (int c = 0; c < 4; ++c)
                    C = __builtin_amdgcn_mfma_f32_16x16x32_bf16(A[mi][c], B[c], C, 0, 0, 0);
                #pragma unroll
                for (int r = 0; r < 4; ++r) {
                    float dot = C[r];
                    float e = exp2f(dot * 2.885390082f - M2);
                    int i = mi*4 + r;
                    sE[i] += e;
                    if ((mm >> i) & 1) { sP[i] += dot; sC[i] += 1.f; }
                }
            }
        }
    }

    #pragma unroll
    for (int mi = 0; mi < 2; ++mi) {
        int m = wv + mi*4;
        if (m < 7) {
            #pragma unroll
            for (int r = 0; r < 4; ++r) {
                int i = mi*4 + r;
                float s = sE[i], qq = sP[i], cc = sC[i];
                #pragma unroll
                for (int off = 1; off < 16; off <<= 1) {
                    s  += __shfl_xor(s,  off);
                    qq += __shfl_xor(qq, off);
                    cc += __shfl_xor(cc, off);
                }
                if (idx15 == 0) {
                    int a = 16*m + 4*kg + r;
                    float* dst = &partials[(((size_t)p*8 + js)*112 + a)*3];
                    dst[0] = s; dst[1] = qq; dst[2] = cc;
                }
            }
        }
    }
}

// ---------------- merge contrastive partials ----------------
__global__ __launch_bounds__(128) void merge_contrast(
    const float* __restrict__ partials, const float* __restrict__ fc_cnt,
    const unsigned int* __restrict__ maxn, float* __restrict__ acc)
{
    int p = blockIdx.x, t = threadIdx.x;
    float pa = 0.f;
    if (t < 100) {
        float s = 0.f, Sp = 0.f, cn = 0.f;
        for (int js = 0; js < 8; ++js) {
            const float* src = &partials[(((size_t)p*8 + js)*112 + t)*3];
            s += src[0]; Sp += src[1]; cn += src[2];
        }
        float M = 2.f * sqrtf(__uint_as_float(*maxn)) + 4.f;
        float lse = M + logf(s);
        pa = lse - 2.f * Sp / fmaxf(cn, 1.f);
    }
    #pragma unroll
    for (int off = 32; off; off >>= 1) pa += __shfl_down(pa, off);
    __shared__ float w2[2];
    if ((t & 63) == 0) w2[t >> 6] = pa;
    __syncthreads();
    if (t == 0) {
        float loss_p = (w2[0] + w2[1]) / 100.f;
        float fcv = fc_cnt[p] / 100.f;
        float inc = ((fcv > 0.1f) && (fcv < 0.9f)) ? 0.f : 1.f;
        atomicAdd(&acc[5], loss_p * inc);
        atomicAdd(&acc[6], inc);
    }
}

// ---------------- final combine ----------------
__global__ void final_kernel(const float* __restrict__ acc,
                             const int* __restrict__ epoch_p,
                             float* __restrict__ out)
{
    if (threadIdx.x == 0 && blockIdx.x == 0) {
        float loss_sup = acc[0] / fmaxf(acc[1], 1.f);
        int epoch = *epoch_p;
        float loss = loss_sup;
        if (epoch >= 5) {
            float contr = acc[5] / fmaxf(acc[6], 1.f);
            float cons  = acc[3] / fmaxf(acc[4], 1.f);
            float ent   = acc[2] / 6400.f;
            float ramp  = fminf(fmaxf((float)epoch / 40.f, 0.f), 1.f);
            float d = 1.f - ramp;
            float cons_w = expf(-5.f * d * d);
            loss = loss_sup + 0.1f * contr + cons_w * cons + 0.01f * ent;
        }
        out[0] = loss;
    }
}

extern "C" void kernel_launch(void* const* d_in, const int* in_sizes, int n_in,
                              void* d_out, int out_size, void* d_ws, size_t ws_size,
                              hipStream_t stream)
{
    const float* x_l      = (const float*)d_in[0];
    const int*   y_l      = (const int*)  d_in[1];
    const float* x_ul     = (const float*)d_in[2];
    const int*   epoch    = (const int*)  d_in[3];
    const float* proj_ema = (const float*)d_in[4];
    const float* z_ema    = (const float*)d_in[5];
    const float* W1       = (const float*)d_in[6];
    const float* W2       = (const float*)d_in[7];
    const float* W3       = (const float*)d_in[8];
    const float* Wc       = (const float*)d_in[9];
    const float* bc       = (const float*)d_in[10];
    const float* Wp       = (const float*)d_in[11];
    float* out = (float*)d_out;
    float* ws  = (float*)d_ws;

    u16*   fea1b = (u16*)(ws + WS_FEA1B);
    u16*   fea2b = (u16*)(ws + WS_FEA2B);
    float* fea3l = ws + WS_FEA3L;
    float* fea3u = ws + WS_FEA3U;
    float* zls   = ws + WS_ZLS;
    float* zul   = ws + WS_ZUL;
    u16*   featB = (u16*)(ws + WS_FEATB);
    int*   labA  = (int*)(ws + WS_LAB);
    float* part  = ws + WS_PART;
    float* acc   = ws + WS_ACC;
    float* fc    = ws + WS_FC;
    u16*   wt2   = (u16*)(ws + WS_WT2);
    u16*   wt3   = (u16*)(ws + WS_WT3);
    unsigned int* maxn = (unsigned int*)(acc + 7);

    hipMemsetAsync(acc, 0, (16 + 64) * sizeof(float), stream);
    hipMemsetAsync(zls, 0, 25600 * sizeof(float), stream);   // covers zls+zul

    wtrans<<<1440, 256, 0, stream>>>(W2, W3, wt2, wt3);

    // ---- labeled branch ----
    conv1_k<<<dim3(160, 4), 256, 0, stream>>>(x_l, W1, fea1b);
    conv3x3_mfma<64,128,160,80,true><<<dim3(100, 2, 4), 256, 0, stream>>>(fea1b, wt2, fea2b, nullptr);
    conv3x3_mfma<128,256,80,40,false><<<dim3(25, 4, 4), 256, 0, stream>>>(fea2b, wt3, nullptr, fea3l);
    conv1x1_cls<<<dim3(25, 8), 256, 0, stream>>>(fea3l, Wc, zls);
    loss_sup_kernel<<<256, 256, 0, stream>>>(zls, y_l, bc, acc);

    // ---- unlabeled branch ----
    conv1_k<<<dim3(160, 4), 256, 0, stream>>>(x_ul, W1, fea1b);
    conv3x3_mfma<64,128,160,80,true><<<dim3(100, 2, 4), 256, 0, stream>>>(fea1b, wt2, fea2b, nullptr);
    conv3x3_mfma<128,256,80,40,false><<<dim3(25, 4, 4), 256, 0, stream>>>(fea2b, wt3, nullptr, fea3u);
    conv1x1_cls<<<dim3(25, 8), 256, 0, stream>>>(fea3u, Wc, zul);

    proj_gemm<<<dim3(25, 4), 256, 0, stream>>>(fea3u, Wp, featB);
    ema_scatter<<<100, 256, 0, stream>>>(proj_ema, featB, maxn);
    ul_small_kernel<<<25, 256, 0, stream>>>(zul, z_ema, bc, labA, acc, fc);

    contrast_mfma<<<dim3(8, 64), 256, 0, stream>>>(featB, labA, maxn, part);
    merge_contrast<<<64, 128, 0, stream>>>(part, fc, maxn, acc);
    final_kernel<<<1, 64, 0, stream>>>(acc, epoch, out);
}

// Round 5
// 349.715 us; speedup vs baseline: 11.0296x; 1.3257x over previous
//
#include <hip/hip_runtime.h>
#include <math.h>

typedef unsigned short u16;
typedef __attribute__((ext_vector_type(8))) short bf16x8;
typedef __attribute__((ext_vector_type(4))) float f32x4;

// ---------------- workspace layout (float-element offsets) ----------------
static const size_t WS_FEA1B = 0;          // 4*64*160*160 bf16 -> 3,276,800 slots
static const size_t WS_FEA2B = 3276800;    // 4*128*80*80 bf16  -> 1,638,400 slots
static const size_t WS_FEA3L = 4915200;    // 4*256*40*40 fp32  -> 1,638,400
static const size_t WS_FEA3U = 6553600;    // 1,638,400
static const size_t WS_ZLS   = 8192000;    // 12,800
static const size_t WS_ZUL   = 8204800;    // 12,800
static const size_t WS_FEATB = 8217600;    // 12800*128 bf16 -> 819,200 slots
static const size_t WS_LAB   = 9036800;    // 12,800 int
static const size_t WS_PART  = 9049600;    // 64*8*112*3 = 172,032
static const size_t WS_ACC   = 9221632;    // 16 floats (acc[7] = maxnorm2 bits)
static const size_t WS_FC    = 9221648;    // 64 floats
static const size_t WS_WT2   = 9221712;    // 9*128*64 bf16 -> 36,864 slots
static const size_t WS_WT3   = 9258576;    // 9*256*128 bf16 -> 147,456 slots
static const size_t WS_WPT   = 9406032;    // 128*256 bf16 -> 16,384 slots
// end 9,422,416 floats = 37.7 MB

__device__ inline u16 f2bf(float x) {
    unsigned int u = __float_as_uint(x);
    unsigned int r = u + 0x7fffu + ((u >> 16) & 1u);
    return (u16)(r >> 16);
}

// ---------------- weight transform: conv W -> [tap][co][ci] bf16; Wp -> bf16 ----------------
__global__ __launch_bounds__(256) void wtrans(
    const float* __restrict__ W2, const float* __restrict__ W3,
    const float* __restrict__ Wp,
    u16* __restrict__ wt2, u16* __restrict__ wt3, u16* __restrict__ wpt)
{
    int tid = blockIdx.x * 256 + threadIdx.x;
    if (tid < 73728) {               // W2: Co=128, Ci=64
        int ci = tid & 63, rest = tid >> 6;
        int co = rest & 127, tap = rest >> 7;
        wt2[tid] = f2bf(W2[((size_t)co*64 + ci)*9 + tap]);
    } else if (tid < 368640) {       // W3: Co=256, Ci=128
        int t3 = tid - 73728;
        int ci = t3 & 127, rest = t3 >> 7;
        int co = rest & 255, tap = rest >> 8;
        wt3[t3] = f2bf(W3[((size_t)co*128 + ci)*9 + tap]);
    } else {                         // Wp: [128][256] already K-contiguous
        int tp = tid - 368640;       // < 32768
        wpt[tp] = f2bf(Wp[tp]);
    }
}

// ---------------- conv1: 3->64, 320->160, fp32 compute, bf16 out ----------------
__global__ __launch_bounds__(256) void conv1_k(
    const float* __restrict__ x, const float* __restrict__ W1,
    u16* __restrict__ fea1b)
{
    int oy = blockIdx.x;
    int n  = blockIdx.y;
    int t = threadIdx.x;
    int co = t & 63, g = t >> 6;
    __shared__ float lds[9*324];
    for (int u = t; u < 9*322; u += 256) {
        int plane = u / 322, col = u - plane*322;
        int ci = plane / 3, ky = plane - ci*3;
        int iy = oy*2 + ky;
        float v = 0.f;
        if (iy < 320 && col < 320)
            v = x[(((size_t)n*3 + ci)*320 + iy)*320 + col];
        lds[plane*324 + col] = v;
    }
    __syncthreads();
    float w[27];
    #pragma unroll
    for (int k = 0; k < 27; ++k) w[k] = W1[co*27 + k];
    float acc[40];
    #pragma unroll
    for (int i = 0; i < 40; ++i) acc[i] = 0.f;
    #pragma unroll
    for (int ci = 0; ci < 3; ++ci) {
        #pragma unroll
        for (int ky = 0; ky < 3; ++ky) {
            const float* base = &lds[(ci*3+ky)*324 + g*80];
            const float* wk = &w[(ci*3+ky)*3];
            #pragma unroll
            for (int q = 0; q < 10; ++q) {
                float4 a = *(const float4*)&base[q*8];
                float4 b = *(const float4*)&base[q*8+4];
                float2 c = *(const float2*)&base[q*8+8];
                float xx[10] = {a.x,a.y,a.z,a.w,b.x,b.y,b.z,b.w,c.x,c.y};
                #pragma unroll
                for (int oo = 0; oo < 4; ++oo)
                    acc[q*4+oo] += wk[0]*xx[2*oo] + wk[1]*xx[2*oo+1] + wk[2]*xx[2*oo+2];
            }
        }
    }
    u16* dst = fea1b + (((size_t)n*64 + co)*160 + oy)*160 + g*40;
    #pragma unroll
    for (int i = 0; i < 20; ++i) {
        float v0 = fmaxf(acc[2*i], 0.f), v1 = fmaxf(acc[2*i+1], 0.f);
        ((unsigned int*)dst)[i] = (unsigned int)f2bf(v0) | ((unsigned int)f2bf(v1) << 16);
    }
}

// ---------------- implicit-GEMM MFMA conv 3x3 s2 (+ReLU) ----------------
template<int Ci, int Co, int H, int OH, bool OB>
__global__ __launch_bounds__(256) void conv3x3_mfma(
    const u16* __restrict__ inb, const u16* __restrict__ wt,
    u16* __restrict__ outb, float* __restrict__ outf)
{
    constexpr int TILES = OH/8;
    int tile = blockIdx.x;
    int co0  = blockIdx.y * 64;
    int n    = blockIdx.z;
    int ty = tile / TILES, tx = tile - ty*TILES;
    int oy0 = ty*8, ox0 = tx*8;
    int iy0 = oy0*2, ix0 = ox0*2;
    int t = threadIdx.x, lane = t & 63, wv = t >> 6;
    int idx15 = lane & 15, kg = lane >> 4;

    __shared__ u16 lds[17*18*32];   // 19,584 B

    f32x4 acc[4];
    #pragma unroll
    for (int nt = 0; nt < 4; ++nt) acc[nt] = (f32x4){0.f,0.f,0.f,0.f};

    const u16* ibase = inb + (size_t)n * Ci * H * H;

    for (int c0 = 0; c0 < Ci; c0 += 32) {
        __syncthreads();
        for (int u = t; u < 16*17*18; u += 256) {
            int pr = u / 18, j = u - pr*18;
            int ci2 = pr / 17, iyl = pr - ci2*17;
            int ci_l = ci2*2;
            int iy = iy0 + iyl, ix = ix0 + j;
            unsigned int v = 0;
            if (iy < H && ix < H) {
                const u16* p = ibase + ((size_t)(c0+ci_l)*H + iy)*H + ix;
                v = (unsigned int)p[0] | ((unsigned int)p[(size_t)H*H] << 16);
            }
            int pix = iyl*18 + j;
            int sg = (ci_l >> 3) ^ ((pix >> 1) & 3);
            ((unsigned int*)lds)[(pix*32 + sg*8 + (ci_l & 7)) >> 1] = v;
        }
        __syncthreads();

        bf16x8 A[9];
        const u16* wb = wt + (size_t)(co0 + wv*16 + idx15)*Ci + c0 + kg*8;
        #pragma unroll
        for (int tap = 0; tap < 9; ++tap)
            A[tap] = *(const bf16x8*)(wb + (size_t)tap*Co*Ci);

        #pragma unroll
        for (int tap = 0; tap < 9; ++tap) {
            int ky = tap/3, kx = tap - ky*3;
            #pragma unroll
            for (int nt = 0; nt < 4; ++nt) {
                int l = nt*16 + idx15;
                int pix = (2*(l>>3) + ky)*18 + 2*(l&7) + kx;
                int slot = kg ^ ((pix >> 1) & 3);
                bf16x8 B = *(const bf16x8*)&lds[pix*32 + slot*8];
                acc[nt] = __builtin_amdgcn_mfma_f32_16x16x32_bf16(A[tap], B, acc[nt], 0, 0, 0);
            }
        }
    }

    int co = co0 + wv*16 + kg*4;
    #pragma unroll
    for (int nt = 0; nt < 4; ++nt) {
        int l = nt*16 + idx15;
        int oy = oy0 + (l>>3), ox = ox0 + (l&7);
        #pragma unroll
        for (int r = 0; r < 4; ++r) {
            float v = fmaxf(acc[nt][r], 0.f);
            size_t o = (((size_t)n*Co + co + r)*OH + oy)*OH + ox;
            if (OB) outb[o] = f2bf(v); else outf[o] = v;
        }
    }
}

// ---------------- 1x1 classifier conv, ci-split with atomics (bias in consumers) ----------------
__global__ __launch_bounds__(256) void conv1x1_cls(
    const float* __restrict__ fea, const float* __restrict__ Wc,
    float* __restrict__ z)
{
    int idx = blockIdx.x * 256 + threadIdx.x;   // 6400 px
    int cc0 = blockIdx.y * 32;
    int n = idx / 1600, r = idx - n*1600;
    const float* f = fea + ((size_t)n*256 + cc0)*1600 + r;
    float a0 = 0.f, a1 = 0.f;
    #pragma unroll
    for (int ci = 0; ci < 32; ++ci) {
        float v = f[(size_t)ci*1600];
        a0 += v * Wc[cc0+ci];
        a1 += v * Wc[256+cc0+ci];
    }
    atomicAdd(&z[(size_t)n*3200 + r], a0);
    atomicAdd(&z[(size_t)n*3200 + 1600 + r], a1);
}

// ---------------- supervised CE: grid-stride + block reduce (2 atomics/block) ----------------
__global__ __launch_bounds__(256) void loss_sup_kernel(
    const float* __restrict__ zs, const int* __restrict__ y,
    const float* __restrict__ bc, float* __restrict__ acc)
{
    const float step = 39.0f / 319.0f;
    float b0 = bc[0], b1 = bc[1];
    float vn = 0.f, vd = 0.f;
    for (int idx = blockIdx.x*256 + threadIdx.x; idx < 409600; idx += gridDim.x*256) {
        int n  = idx / 102400;
        int r  = idx - n*102400;
        int oy = r / 320, ox = r - oy*320;
        float ty = (float)oy * step, tx = (float)ox * step;
        int y0 = (int)ty, x0 = (int)tx;
        int y1 = min(y0 + 1, 39), x1 = min(x0 + 1, 39);
        float wy = ty - (float)y0, wx = tx - (float)x0;
        const float* base = zs + (size_t)n * 3200;
        float z[2];
        #pragma unroll
        for (int c = 0; c < 2; ++c) {
            const float* pl = base + c * 1600;
            float v00 = pl[y0*40 + x0], v01 = pl[y0*40 + x1];
            float v10 = pl[y1*40 + x0], v11 = pl[y1*40 + x1];
            float top = v00 * (1.f - wx) + v01 * wx;
            float bot = v10 * (1.f - wx) + v11 * wx;
            z[c] = top * (1.f - wy) + bot * wy + (c ? b1 : b0);
        }
        int lab = y[idx];
        bool valid = (lab != 255);
        int sl = min(max(lab, 0), 1);
        float mz  = fmaxf(z[0], z[1]);
        float lse = mz + logf(expf(z[0]-mz) + expf(z[1]-mz));
        float nll = lse - z[sl];
        if (valid) { vn += nll; vd += 1.f; }
    }
    #pragma unroll
    for (int off = 32; off; off >>= 1) { vn += __shfl_down(vn, off); vd += __shfl_down(vd, off); }
    __shared__ float rb[8];
    int wv = threadIdx.x >> 6;
    if ((threadIdx.x & 63) == 0) { rb[wv*2] = vn; rb[wv*2+1] = vd; }
    __syncthreads();
    if (threadIdx.x == 0) {
        atomicAdd(&acc[0], rb[0]+rb[2]+rb[4]+rb[6]);
        atomicAdd(&acc[1], rb[1]+rb[3]+rb[5]+rb[7]);
    }
}

// ---------------- unlabeled small losses + pseudo labels + patch counts ----------------
__global__ __launch_bounds__(256) void ul_small_kernel(
    const float* __restrict__ z_ul, const float* __restrict__ z_ema,
    const float* __restrict__ bc,
    int* __restrict__ lab_all, float* __restrict__ acc, float* __restrict__ fc_cnt)
{
    int idx = blockIdx.x * 256 + threadIdx.x;   // 6400
    int n = idx / 1600;
    int r = idx - n*1600;
    int yy = r / 40, xx = r - yy*40;
    float z0 = z_ul[(size_t)n*3200 + r] + bc[0];
    float z1 = z_ul[(size_t)n*3200 + 1600 + r] + bc[1];
    float m = fmaxf(z0, z1);
    float e0 = expf(z0 - m), e1 = expf(z1 - m);
    float lse = m + logf(e0 + e1);
    float lp0 = z0 - lse, lp1 = z1 - lse;
    float p0 = expf(lp0), p1 = expf(lp1);
    float ent = -(p0*lp0 + p1*lp1);
    int pl = (z1 > z0) ? 1 : 0;
    float ze0 = z_ema[(size_t)n*3200 + r], ze1 = z_ema[(size_t)n*3200 + 1600 + r];
    float me = fmaxf(ze0, ze1);
    float f0 = expf(ze0 - me), f1 = expf(ze1 - me);
    float maxp = 1.f / (f0 + f1);
    int ple = (ze1 > ze0) ? 1 : 0;
    bool mask = (maxp > 0.6f);
    float nll = lse - (ple ? z1 : z0);

    int pi = yy / 10, hi = yy % 10, pj = xx / 10, wi = xx % 10;
    int patch = (pi*4 + pj)*4 + n;
    int row = patch * 100 + hi*10 + wi;
    lab_all[row]        = pl;
    lab_all[6400 + row] = ple;
    atomicAdd(&fc_cnt[patch], (float)pl);

    float cn = mask ? nll : 0.f;
    float cd = mask ? 1.f : 0.f;
    #pragma unroll
    for (int off = 32; off; off >>= 1) {
        ent += __shfl_down(ent, off);
        cn  += __shfl_down(cn, off);
        cd  += __shfl_down(cd, off);
    }
    if ((threadIdx.x & 63) == 0) {
        atomicAdd(&acc[2], ent);
        atomicAdd(&acc[3], cn);
        atomicAdd(&acc[4], cd);
    }
}

// ---------------- projector: MFMA GEMM + L2 normalize + scatter ----------------
// Block = 64 px; A = WpT (bf16, regs), B = fea tile staged to LDS as bf16 ci-pairs.
// Swizzle x(cp) = (cp&3)|(((cp>>2)&3)<<4): <=2-way banks on both store and load.
__global__ __launch_bounds__(256) void proj_mfma(
    const float* __restrict__ fea, const u16* __restrict__ wpt,
    u16* __restrict__ feat)
{
    __shared__ unsigned int lds[128*64];   // 32 KB: [cp][px ^ x(cp)]
    __shared__ float nrm[4][64];
    int b = blockIdx.x;              // 0..99
    int n = b / 25;
    int r0 = (b - n*25) * 64;
    int t = threadIdx.x, lane = t & 63, wv = t >> 6;
    int idx15 = lane & 15, kg = lane >> 4;

    // stage 256ci x 64px fp32 -> bf16 pairs
    const float* fb = fea + (size_t)n * 256 * 1600 + r0;
    #pragma unroll
    for (int i = 0; i < 8; ++i) {
        int flat = i*256 + t;
        int px4 = flat & 15, cp = flat >> 4;
        float4 v0 = *(const float4*)&fb[(size_t)(2*cp)*1600 + px4*4];
        float4 v1 = *(const float4*)&fb[(size_t)(2*cp+1)*1600 + px4*4];
        int x = (cp & 3) | (((cp >> 2) & 3) << 4);
        float a0[4] = {v0.x, v0.y, v0.z, v0.w};
        float a1[4] = {v1.x, v1.y, v1.z, v1.w};
        #pragma unroll
        for (int j = 0; j < 4; ++j) {
            unsigned int pk = (unsigned int)f2bf(a0[j]) | ((unsigned int)f2bf(a1[j]) << 16);
            lds[cp*64 + ((px4*4 + j) ^ x)] = pk;
        }
    }

    // A-frags in registers: wave wv owns ch [wv*32, wv*32+32)
    bf16x8 A[2][8];
    #pragma unroll
    for (int mi = 0; mi < 2; ++mi) {
        const u16* wrow = wpt + (size_t)(wv*32 + mi*16 + idx15)*256 + kg*8;
        #pragma unroll
        for (int ks = 0; ks < 8; ++ks)
            A[mi][ks] = *(const bf16x8*)(wrow + ks*32);
    }
    __syncthreads();

    f32x4 acc[2][4];
    #pragma unroll
    for (int mi = 0; mi < 2; ++mi)
        #pragma unroll
        for (int nt = 0; nt < 4; ++nt) acc[mi][nt] = (f32x4){0.f,0.f,0.f,0.f};

    #pragma unroll
    for (int ks = 0; ks < 8; ++ks) {
        #pragma unroll
        for (int nt = 0; nt < 4; ++nt) {
            union { unsigned int u[4]; bf16x8 v; } bw;
            #pragma unroll
            for (int w = 0; w < 4; ++w) {
                int cp = ks*16 + kg*4 + w;
                int x = (cp & 3) | (((cp >> 2) & 3) << 4);
                bw.u[w] = lds[cp*64 + ((nt*16 + idx15) ^ x)];
            }
            acc[0][nt] = __builtin_amdgcn_mfma_f32_16x16x32_bf16(A[0][ks], bw.v, acc[0][nt], 0, 0, 0);
            acc[1][nt] = __builtin_amdgcn_mfma_f32_16x16x32_bf16(A[1][ks], bw.v, acc[1][nt], 0, 0, 0);
        }
    }

    // per-px norm^2: this wave's 32 ch -> nrm[wv][px]
    #pragma unroll
    for (int nt = 0; nt < 4; ++nt) {
        float sq = 0.f;
        #pragma unroll
        for (int mi = 0; mi < 2; ++mi)
            #pragma unroll
            for (int r = 0; r < 4; ++r) sq += acc[mi][nt][r]*acc[mi][nt][r];
        sq += __shfl_xor(sq, 16);
        sq += __shfl_xor(sq, 32);
        if (kg == 0) nrm[wv][nt*16 + idx15] = sq;
    }
    __syncthreads();

    #pragma unroll
    for (int nt = 0; nt < 4; ++nt) {
        int px = nt*16 + idx15;
        float tot = nrm[0][px] + nrm[1][px] + nrm[2][px] + nrm[3][px];
        float scale = 1.f / fmaxf(sqrtf(tot), 1e-12f);
        int r = r0 + px;
        int yy = r / 40, xx = r - yy*40;
        int row = ((yy/10*4 + xx/10)*4 + n)*100 + (yy%10)*10 + (xx%10);
        unsigned int* dst = (unsigned int*)(feat + (size_t)row*128) + wv*16 + kg*2;
        #pragma unroll
        for (int mi = 0; mi < 2; ++mi) {
            #pragma unroll
            for (int pr = 0; pr < 2; ++pr) {
                unsigned int pk = (unsigned int)f2bf(acc[mi][nt][2*pr]*scale)
                                | ((unsigned int)f2bf(acc[mi][nt][2*pr+1]*scale) << 16);
                dst[mi*8 + pr] = pk;
            }
        }
    }
}

// ---------------- EMA scatter: coalesced tile-transpose + 1 atomicMax/block ----------------
__global__ __launch_bounds__(256) void ema_scatter(
    const float* __restrict__ ema, u16* __restrict__ feat,
    unsigned int* __restrict__ maxn)
{
    __shared__ float lds[128*64];    // 32 KB, col = pxl ^ ((c>>5)<<3)
    int b = blockIdx.x;              // 0..99
    int n = b / 25;
    int r0 = (b - n*25) * 64;
    int t = threadIdx.x, lane = t & 63, wv = t >> 6;

    const float* src = ema + ((size_t)n*128 + wv*32)*1600 + r0 + lane;
    int scol = lane ^ (wv << 3);
    #pragma unroll
    for (int cc = 0; cc < 32; ++cc)
        lds[(wv*32 + cc)*64 + scol] = src[(size_t)cc*1600];
    __syncthreads();

    int pxl = t >> 2, cq = t & 3;
    int r = r0 + pxl;
    int yy = r / 40, xx = r - yy*40;
    int row = 6400 + ((yy/10*4 + xx/10)*4 + n)*100 + (yy%10)*10 + (xx%10);
    int rcol = pxl ^ (cq << 3);
    float sq = 0.f;
    unsigned int pk[16];
    #pragma unroll
    for (int i = 0; i < 16; ++i) {
        float v0 = lds[(cq*32 + 2*i)*64 + rcol];
        float v1 = lds[(cq*32 + 2*i + 1)*64 + rcol];
        sq += v0*v0 + v1*v1;
        pk[i] = (unsigned int)f2bf(v0) | ((unsigned int)f2bf(v1) << 16);
    }
    u16* dst = feat + (size_t)row*128 + cq*32;
    #pragma unroll
    for (int i = 0; i < 4; ++i)
        *(uint4*)&((unsigned int*)dst)[i*4] = *(uint4*)&pk[i*4];

    sq += __shfl_xor(sq, 1);
    sq += __shfl_xor(sq, 2);
    float mx = sq;
    #pragma unroll
    for (int off = 4; off < 64; off <<= 1) mx = fmaxf(mx, __shfl_xor(mx, off));
    __shared__ float red[4];
    if (lane == 0) red[wv] = mx;
    __syncthreads();
    if (t == 0)
        atomicMax(maxn, __float_as_uint(fmaxf(fmaxf(red[0], red[1]),
                                              fmaxf(red[2], red[3]))));
}

// ---------------- contrastive: MFMA streaming fixed-bound softmax GEMM ----------------
__global__ __launch_bounds__(256) void contrast_mfma(
    const u16* __restrict__ feat, const int* __restrict__ lab,
    const unsigned int* __restrict__ maxn, float* __restrict__ partials)
{
    int js = blockIdx.x;      // 0..7
    int p  = blockIdx.y;      // 0..63
    int t = threadIdx.x, lane = t & 63, wv = t >> 6;
    int idx15 = lane & 15;
    int kg = lane >> 4;

    float M = 2.f * sqrtf(__uint_as_float(*maxn)) + 4.f;
    float M2 = M * 1.44269504f;

    bf16x8 A[2][4];
    bf16x8 zz = {0,0,0,0,0,0,0,0};
    #pragma unroll
    for (int mi = 0; mi < 2; ++mi) {
        int m = wv + mi*4;
        #pragma unroll
        for (int c = 0; c < 4; ++c) {
            int a = 16*m + idx15;
            A[mi][c] = (m < 7 && a < 100)
                ? *(const bf16x8*)&feat[(size_t)(p*100 + a)*128 + c*32 + kg*8]
                : zz;
        }
    }
    unsigned int labmask = 0;
    #pragma unroll
    for (int mi = 0; mi < 2; ++mi) {
        int m = wv + mi*4;
        if (m < 7) {
            #pragma unroll
            for (int r = 0; r < 4; ++r) {
                int a = 16*m + 4*kg + r;
                int la = (a < 100) ? lab[p*100 + a] : 0;
                labmask |= (unsigned int)(la & 1) << (mi*4 + r);
            }
        }
    }

    int jbase = js * 1600;
    float sE[8] = {}, sP[8] = {}, sC[8] = {};

    for (int jt = 0; jt < 100; ++jt) {
        int jrow = jbase + jt*16;
        bf16x8 B[4];
        #pragma unroll
        for (int c = 0; c < 4; ++c)
            B[c] = *(const bf16x8*)&feat[(size_t)(jrow + idx15)*128 + c*32 + kg*8];
        int lj = lab[jrow + idx15];
        unsigned int mm = lj ? labmask : ~labmask;
        #pragma unroll
        for (int mi = 0; mi < 2; ++mi) {
            int m = wv + mi*4;
            if (m < 7) {
                f32x4 C = {0.f, 0.f, 0.f, 0.f};
                #pragma unroll
                for (int c = 0; c < 4; ++c)
                    C = __builtin_amdgcn_mfma_f32_16x16x32_bf16(A[mi][c], B[c], C, 0, 0, 0);
                #pragma unroll
                for (int r = 0; r < 4; ++r) {
                    float dot = C[r];
                    float e = exp2f(dot * 2.885390082f - M2);
                    int i = mi*4 + r;
                    sE[i] += e;
                    if ((mm >> i) & 1) { sP[i] += dot; sC[i] += 1.f; }
                }
            }
        }
    }

    #pragma unroll
    for (int mi = 0; mi < 2; ++mi) {
        int m = wv + mi*4;
        if (m < 7) {
            #pragma unroll
            for (int r = 0; r < 4; ++r) {
                int i = mi*4 + r;
                float s = sE[i], qq = sP[i], cc = sC[i];
                #pragma unroll
                for (int off = 1; off < 16; off <<= 1) {
                    s  += __shfl_xor(s,  off);
                    qq += __shfl_xor(qq, off);
                    cc += __shfl_xor(cc, off);
                }
                if (idx15 == 0) {
                    int a = 16*m + 4*kg + r;
                    float* dst = &partials[(((size_t)p*8 + js)*112 + a)*3];
                    dst[0] = s; dst[1] = qq; dst[2] = cc;
                }
            }
        }
    }
}

// ---------------- merge contrastive partials ----------------
__global__ __launch_bounds__(128) void merge_contrast(
    const float* __restrict__ partials, const float* __restrict__ fc_cnt,
    const unsigned int* __restrict__ maxn, float* __restrict__ acc)
{
    int p = blockIdx.x, t = threadIdx.x;
    float pa = 0.f;
    if (t < 100) {
        float s = 0.f, Sp = 0.f, cn = 0.f;
        for (int js = 0; js < 8; ++js) {
            const float* src = &partials[(((size_t)p*8 + js)*112 + t)*3];
            s += src[0]; Sp += src[1]; cn += src[2];
        }
        float M = 2.f * sqrtf(__uint_as_float(*maxn)) + 4.f;
        float lse = M + logf(s);
        pa = lse - 2.f * Sp / fmaxf(cn, 1.f);
    }
    #pragma unroll
    for (int off = 32; off; off >>= 1) pa += __shfl_down(pa, off);
    __shared__ float w2[2];
    if ((t & 63) == 0) w2[t >> 6] = pa;
    __syncthreads();
    if (t == 0) {
        float loss_p = (w2[0] + w2[1]) / 100.f;
        float fcv = fc_cnt[p] / 100.f;
        float inc = ((fcv > 0.1f) && (fcv < 0.9f)) ? 0.f : 1.f;
        atomicAdd(&acc[5], loss_p * inc);
        atomicAdd(&acc[6], inc);
    }
}

// ---------------- final combine ----------------
__global__ void final_kernel(const float* __restrict__ acc,
                             const int* __restrict__ epoch_p,
                             float* __restrict__ out)
{
    if (threadIdx.x == 0 && blockIdx.x == 0) {
        float loss_sup = acc[0] / fmaxf(acc[1], 1.f);
        int epoch = *epoch_p;
        float loss = loss_sup;
        if (epoch >= 5) {
            float contr = acc[5] / fmaxf(acc[6], 1.f);
            float cons  = acc[3] / fmaxf(acc[4], 1.f);
            float ent   = acc[2] / 6400.f;
            float ramp  = fminf(fmaxf((float)epoch / 40.f, 0.f), 1.f);
            float d = 1.f - ramp;
            float cons_w = expf(-5.f * d * d);
            loss = loss_sup + 0.1f * contr + cons_w * cons + 0.01f * ent;
        }
        out[0] = loss;
    }
}

extern "C" void kernel_launch(void* const* d_in, const int* in_sizes, int n_in,
                              void* d_out, int out_size, void* d_ws, size_t ws_size,
                              hipStream_t stream)
{
    const float* x_l      = (const float*)d_in[0];
    const int*   y_l      = (const int*)  d_in[1];
    const float* x_ul     = (const float*)d_in[2];
    const int*   epoch    = (const int*)  d_in[3];
    const float* proj_ema = (const float*)d_in[4];
    const float* z_ema    = (const float*)d_in[5];
    const float* W1       = (const float*)d_in[6];
    const float* W2       = (const float*)d_in[7];
    const float* W3       = (const float*)d_in[8];
    const float* Wc       = (const float*)d_in[9];
    const float* bc       = (const float*)d_in[10];
    const float* Wp       = (const float*)d_in[11];
    float* out = (float*)d_out;
    float* ws  = (float*)d_ws;

    u16*   fea1b = (u16*)(ws + WS_FEA1B);
    u16*   fea2b = (u16*)(ws + WS_FEA2B);
    float* fea3l = ws + WS_FEA3L;
    float* fea3u = ws + WS_FEA3U;
    float* zls   = ws + WS_ZLS;
    float* zul   = ws + WS_ZUL;
    u16*   featB = (u16*)(ws + WS_FEATB);
    int*   labA  = (int*)(ws + WS_LAB);
    float* part  = ws + WS_PART;
    float* acc   = ws + WS_ACC;
    float* fc    = ws + WS_FC;
    u16*   wt2   = (u16*)(ws + WS_WT2);
    u16*   wt3   = (u16*)(ws + WS_WT3);
    u16*   wpt   = (u16*)(ws + WS_WPT);
    unsigned int* maxn = (unsigned int*)(acc + 7);

    hipMemsetAsync(acc, 0, (16 + 64) * sizeof(float), stream);
    hipMemsetAsync(zls, 0, 25600 * sizeof(float), stream);   // covers zls+zul

    wtrans<<<1568, 256, 0, stream>>>(W2, W3, Wp, wt2, wt3, wpt);

    // ---- labeled branch ----
    conv1_k<<<dim3(160, 4), 256, 0, stream>>>(x_l, W1, fea1b);
    conv3x3_mfma<64,128,160,80,true><<<dim3(100, 2, 4), 256, 0, stream>>>(fea1b, wt2, fea2b, nullptr);
    conv3x3_mfma<128,256,80,40,false><<<dim3(25, 4, 4), 256, 0, stream>>>(fea2b, wt3, nullptr, fea3l);
    conv1x1_cls<<<dim3(25, 8), 256, 0, stream>>>(fea3l, Wc, zls);
    loss_sup_kernel<<<256, 256, 0, stream>>>(zls, y_l, bc, acc);

    // ---- unlabeled branch ----
    conv1_k<<<dim3(160, 4), 256, 0, stream>>>(x_ul, W1, fea1b);
    conv3x3_mfma<64,128,160,80,true><<<dim3(100, 2, 4), 256, 0, stream>>>(fea1b, wt2, fea2b, nullptr);
    conv3x3_mfma<128,256,80,40,false><<<dim3(25, 4, 4), 256, 0, stream>>>(fea2b, wt3, nullptr, fea3u);
    conv1x1_cls<<<dim3(25, 8), 256, 0, stream>>>(fea3u, Wc, zul);

    proj_mfma<<<100, 256, 0, stream>>>(fea3u, wpt, featB);
    ema_scatter<<<100, 256, 0, stream>>>(proj_ema, featB, maxn);
    ul_small_kernel<<<25, 256, 0, stream>>>(zul, z_ema, bc, labA, acc, fc);

    contrast_mfma<<<dim3(8, 64), 256, 0, stream>>>(featB, labA, maxn, part);
    merge_contrast<<<64, 128, 0, stream>>>(part, fc, maxn, acc);
    final_kernel<<<1, 64, 0, stream>>>(acc, epoch, out);
}

// Round 6
// 320.566 us; speedup vs baseline: 12.0325x; 1.0909x over previous
//
#include <hip/hip_runtime.h>
#include <math.h>

typedef unsigned short u16;
typedef __attribute__((ext_vector_type(8))) short bf16x8;
typedef __attribute__((ext_vector_type(4))) float f32x4;

// ---------------- workspace layout (float-element offsets) ----------------
static const size_t WS_FEA1B = 0;          // 8*64*160*160 bf16 -> 6,553,600 slots
static const size_t WS_FEA2B = 6553600;    // 8*128*80*80 bf16  -> 3,276,800 slots
static const size_t WS_FEA3  = 9830400;    // 8*256*40*40 fp32  -> 3,276,800 (n<4 labeled, n>=4 unlabeled)
static const size_t WS_ZLS   = 13107200;   // 12,800 (labeled logits)
static const size_t WS_ZUL   = 13120000;   // 12,800 (unlabeled logits, contiguous after ZLS)
static const size_t WS_FEATB = 13132800;   // 12800*128 bf16 -> 819,200 slots
static const size_t WS_LAB   = 13952000;   // 12,800 int
static const size_t WS_PART  = 13964800;   // 64*8*112 = 57,344
static const size_t WS_ACC   = 14022144;   // 16 floats (acc[7]=maxnorm2 bits, acc[8]=N1)
static const size_t WS_FC    = 14022160;   // 64 floats
static const size_t WS_CSUM  = 14022224;   // 2*128 class feature sums
static const size_t WS_WT2   = 14022480;   // 9*128*64 bf16 -> 36,864 slots
static const size_t WS_WT3   = 14059344;   // 9*256*128 bf16 -> 147,456 slots
static const size_t WS_WPT   = 14206800;   // 128*256 bf16 -> 16,384 slots
// end 14,223,184 floats = 56.9 MB

__device__ inline u16 f2bf(float x) {
    unsigned int u = __float_as_uint(x);
    unsigned int r = u + 0x7fffu + ((u >> 16) & 1u);
    return (u16)(r >> 16);
}

// ---------------- weight transform: conv W -> [tap][co][ci] bf16; Wp -> bf16 ----------------
__global__ __launch_bounds__(256) void wtrans(
    const float* __restrict__ W2, const float* __restrict__ W3,
    const float* __restrict__ Wp,
    u16* __restrict__ wt2, u16* __restrict__ wt3, u16* __restrict__ wpt)
{
    int tid = blockIdx.x * 256 + threadIdx.x;
    if (tid < 73728) {               // W2: Co=128, Ci=64
        int ci = tid & 63, rest = tid >> 6;
        int co = rest & 127, tap = rest >> 7;
        wt2[tid] = f2bf(W2[((size_t)co*64 + ci)*9 + tap]);
    } else if (tid < 368640) {       // W3: Co=256, Ci=128
        int t3 = tid - 73728;
        int ci = t3 & 127, rest = t3 >> 7;
        int co = rest & 255, tap = rest >> 8;
        wt3[t3] = f2bf(W3[((size_t)co*128 + ci)*9 + tap]);
    } else {                         // Wp: [128][256] already K-contiguous
        int tp = tid - 368640;       // < 32768
        wpt[tp] = f2bf(Wp[tp]);
    }
}

// ---------------- conv1: 3->64, 320->160, both branches (n 0..7), bf16 out ----------------
__global__ __launch_bounds__(256) void conv1_k(
    const float* __restrict__ x_l, const float* __restrict__ x_ul,
    const float* __restrict__ W1, u16* __restrict__ fea1b)
{
    int oy = blockIdx.x;
    int n  = blockIdx.y;
    const float* x = (n < 4) ? x_l + (size_t)n*307200
                             : x_ul + (size_t)(n-4)*307200;
    int t = threadIdx.x;
    int co = t & 63, g = t >> 6;
    __shared__ float lds[9*324];
    for (int u = t; u < 9*322; u += 256) {
        int plane = u / 322, col = u - plane*322;
        int ci = plane / 3, ky = plane - ci*3;
        int iy = oy*2 + ky;
        float v = 0.f;
        if (iy < 320 && col < 320)
            v = x[((size_t)ci*320 + iy)*320 + col];
        lds[plane*324 + col] = v;
    }
    __syncthreads();
    float w[27];
    #pragma unroll
    for (int k = 0; k < 27; ++k) w[k] = W1[co*27 + k];
    float acc[40];
    #pragma unroll
    for (int i = 0; i < 40; ++i) acc[i] = 0.f;
    #pragma unroll
    for (int ci = 0; ci < 3; ++ci) {
        #pragma unroll
        for (int ky = 0; ky < 3; ++ky) {
            const float* base = &lds[(ci*3+ky)*324 + g*80];
            const float* wk = &w[(ci*3+ky)*3];
            #pragma unroll
            for (int q = 0; q < 10; ++q) {
                float4 a = *(const float4*)&base[q*8];
                float4 b = *(const float4*)&base[q*8+4];
                float2 c = *(const float2*)&base[q*8+8];
                float xx[10] = {a.x,a.y,a.z,a.w,b.x,b.y,b.z,b.w,c.x,c.y};
                #pragma unroll
                for (int oo = 0; oo < 4; ++oo)
                    acc[q*4+oo] += wk[0]*xx[2*oo] + wk[1]*xx[2*oo+1] + wk[2]*xx[2*oo+2];
            }
        }
    }
    u16* dst = fea1b + (((size_t)n*64 + co)*160 + oy)*160 + g*40;
    #pragma unroll
    for (int i = 0; i < 20; ++i) {
        float v0 = fmaxf(acc[2*i], 0.f), v1 = fmaxf(acc[2*i+1], 0.f);
        ((unsigned int*)dst)[i] = (unsigned int)f2bf(v0) | ((unsigned int)f2bf(v1) << 16);
    }
}

// ---------------- implicit-GEMM MFMA conv 3x3 s2 (+ReLU) ----------------
template<int Ci, int Co, int H, int OH, bool OB>
__global__ __launch_bounds__(256) void conv3x3_mfma(
    const u16* __restrict__ inb, const u16* __restrict__ wt,
    u16* __restrict__ outb, float* __restrict__ outf)
{
    constexpr int TILES = OH/8;
    int tile = blockIdx.x;
    int co0  = blockIdx.y * 64;
    int n    = blockIdx.z;
    int ty = tile / TILES, tx = tile - ty*TILES;
    int oy0 = ty*8, ox0 = tx*8;
    int iy0 = oy0*2, ix0 = ox0*2;
    int t = threadIdx.x, lane = t & 63, wv = t >> 6;
    int idx15 = lane & 15, kg = lane >> 4;

    __shared__ u16 lds[17*18*32];   // 19,584 B

    f32x4 acc[4];
    #pragma unroll
    for (int nt = 0; nt < 4; ++nt) acc[nt] = (f32x4){0.f,0.f,0.f,0.f};

    const u16* ibase = inb + (size_t)n * Ci * H * H;

    for (int c0 = 0; c0 < Ci; c0 += 32) {
        __syncthreads();
        for (int u = t; u < 16*17*18; u += 256) {
            int pr = u / 18, j = u - pr*18;
            int ci2 = pr / 17, iyl = pr - ci2*17;
            int ci_l = ci2*2;
            int iy = iy0 + iyl, ix = ix0 + j;
            unsigned int v = 0;
            if (iy < H && ix < H) {
                const u16* p = ibase + ((size_t)(c0+ci_l)*H + iy)*H + ix;
                v = (unsigned int)p[0] | ((unsigned int)p[(size_t)H*H] << 16);
            }
            int pix = iyl*18 + j;
            int sg = (ci_l >> 3) ^ ((pix >> 1) & 3);
            ((unsigned int*)lds)[(pix*32 + sg*8 + (ci_l & 7)) >> 1] = v;
        }
        __syncthreads();

        bf16x8 A[9];
        const u16* wb = wt + (size_t)(co0 + wv*16 + idx15)*Ci + c0 + kg*8;
        #pragma unroll
        for (int tap = 0; tap < 9; ++tap)
            A[tap] = *(const bf16x8*)(wb + (size_t)tap*Co*Ci);

        #pragma unroll
        for (int tap = 0; tap < 9; ++tap) {
            int ky = tap/3, kx = tap - ky*3;
            #pragma unroll
            for (int nt = 0; nt < 4; ++nt) {
                int l = nt*16 + idx15;
                int pix = (2*(l>>3) + ky)*18 + 2*(l&7) + kx;
                int slot = kg ^ ((pix >> 1) & 3);
                bf16x8 B = *(const bf16x8*)&lds[pix*32 + slot*8];
                acc[nt] = __builtin_amdgcn_mfma_f32_16x16x32_bf16(A[tap], B, acc[nt], 0, 0, 0);
            }
        }
    }

    int co = co0 + wv*16 + kg*4;
    #pragma unroll
    for (int nt = 0; nt < 4; ++nt) {
        int l = nt*16 + idx15;
        int oy = oy0 + (l>>3), ox = ox0 + (l&7);
        #pragma unroll
        for (int r = 0; r < 4; ++r) {
            float v = fmaxf(acc[nt][r], 0.f);
            size_t o = (((size_t)n*Co + co + r)*OH + oy)*OH + ox;
            if (OB) outb[o] = f2bf(v); else outf[o] = v;
        }
    }
}

// ---------------- 1x1 classifier conv over both branches, ci-split atomics ----------------
__global__ __launch_bounds__(256) void conv1x1_cls(
    const float* __restrict__ fea, const float* __restrict__ Wc,
    float* __restrict__ z)
{
    int idx = blockIdx.x * 256 + threadIdx.x;   // 12800 px (8 images)
    int cc0 = blockIdx.y * 32;
    int n = idx / 1600, r = idx - n*1600;
    const float* f = fea + ((size_t)n*256 + cc0)*1600 + r;
    float a0 = 0.f, a1 = 0.f;
    #pragma unroll
    for (int ci = 0; ci < 32; ++ci) {
        float v = f[(size_t)ci*1600];
        a0 += v * Wc[cc0+ci];
        a1 += v * Wc[256+cc0+ci];
    }
    atomicAdd(&z[(size_t)n*3200 + r], a0);
    atomicAdd(&z[(size_t)n*3200 + 1600 + r], a1);
}

// ---------------- supervised CE: grid-stride + block reduce (2 atomics/block) ----------------
__global__ __launch_bounds__(256) void loss_sup_kernel(
    const float* __restrict__ zs, const int* __restrict__ y,
    const float* __restrict__ bc, float* __restrict__ acc)
{
    const float step = 39.0f / 319.0f;
    float b0 = bc[0], b1 = bc[1];
    float vn = 0.f, vd = 0.f;
    for (int idx = blockIdx.x*256 + threadIdx.x; idx < 409600; idx += gridDim.x*256) {
        int n  = idx / 102400;
        int r  = idx - n*102400;
        int oy = r / 320, ox = r - oy*320;
        float ty = (float)oy * step, tx = (float)ox * step;
        int y0 = (int)ty, x0 = (int)tx;
        int y1 = min(y0 + 1, 39), x1 = min(x0 + 1, 39);
        float wy = ty - (float)y0, wx = tx - (float)x0;
        const float* base = zs + (size_t)n * 3200;
        float z[2];
        #pragma unroll
        for (int c = 0; c < 2; ++c) {
            const float* pl = base + c * 1600;
            float v00 = pl[y0*40 + x0], v01 = pl[y0*40 + x1];
            float v10 = pl[y1*40 + x0], v11 = pl[y1*40 + x1];
            float top = v00 * (1.f - wx) + v01 * wx;
            float bot = v10 * (1.f - wx) + v11 * wx;
            z[c] = top * (1.f - wy) + bot * wy + (c ? b1 : b0);
        }
        int lab = y[idx];
        bool valid = (lab != 255);
        int sl = min(max(lab, 0), 1);
        float mz  = fmaxf(z[0], z[1]);
        float lse = mz + logf(expf(z[0]-mz) + expf(z[1]-mz));
        float nll = lse - z[sl];
        if (valid) { vn += nll; vd += 1.f; }
    }
    #pragma unroll
    for (int off = 32; off; off >>= 1) { vn += __shfl_down(vn, off); vd += __shfl_down(vd, off); }
    __shared__ float rb[8];
    int wv = threadIdx.x >> 6;
    if ((threadIdx.x & 63) == 0) { rb[wv*2] = vn; rb[wv*2+1] = vd; }
    __syncthreads();
    if (threadIdx.x == 0) {
        atomicAdd(&acc[0], rb[0]+rb[2]+rb[4]+rb[6]);
        atomicAdd(&acc[1], rb[1]+rb[3]+rb[5]+rb[7]);
    }
}

// ---------------- unlabeled small losses + pseudo labels + patch counts ----------------
__global__ __launch_bounds__(256) void ul_small_kernel(
    const float* __restrict__ z_ul, const float* __restrict__ z_ema,
    const float* __restrict__ bc,
    int* __restrict__ lab_all, float* __restrict__ acc, float* __restrict__ fc_cnt)
{
    int idx = blockIdx.x * 256 + threadIdx.x;   // 6400
    int n = idx / 1600;
    int r = idx - n*1600;
    int yy = r / 40, xx = r - yy*40;
    float z0 = z_ul[(size_t)n*3200 + r] + bc[0];
    float z1 = z_ul[(size_t)n*3200 + 1600 + r] + bc[1];
    float m = fmaxf(z0, z1);
    float e0 = expf(z0 - m), e1 = expf(z1 - m);
    float lse = m + logf(e0 + e1);
    float lp0 = z0 - lse, lp1 = z1 - lse;
    float p0 = expf(lp0), p1 = expf(lp1);
    float ent = -(p0*lp0 + p1*lp1);
    int pl = (z1 > z0) ? 1 : 0;
    float ze0 = z_ema[(size_t)n*3200 + r], ze1 = z_ema[(size_t)n*3200 + 1600 + r];
    float me = fmaxf(ze0, ze1);
    float f0 = expf(ze0 - me), f1 = expf(ze1 - me);
    float maxp = 1.f / (f0 + f1);
    int ple = (ze1 > ze0) ? 1 : 0;
    bool mask = (maxp > 0.6f);
    float nll = lse - (ple ? z1 : z0);

    int pi = yy / 10, hi = yy % 10, pj = xx / 10, wi = xx % 10;
    int patch = (pi*4 + pj)*4 + n;
    int row = patch * 100 + hi*10 + wi;
    lab_all[row]        = pl;
    lab_all[6400 + row] = ple;
    atomicAdd(&fc_cnt[patch], (float)pl);

    float cn = mask ? nll : 0.f;
    float cd = mask ? 1.f : 0.f;
    #pragma unroll
    for (int off = 32; off; off >>= 1) {
        ent += __shfl_down(ent, off);
        cn  += __shfl_down(cn, off);
        cd  += __shfl_down(cd, off);
    }
    if ((threadIdx.x & 63) == 0) {
        atomicAdd(&acc[2], ent);
        atomicAdd(&acc[3], cn);
        atomicAdd(&acc[4], cd);
    }
}

// ---------------- projector: MFMA GEMM + L2 normalize + scatter ----------------
__global__ __launch_bounds__(256) void proj_mfma(
    const float* __restrict__ fea, const u16* __restrict__ wpt,
    u16* __restrict__ feat)
{
    __shared__ unsigned int lds[128*64];   // 32 KB: [cp][px ^ x(cp)]
    __shared__ float nrm[4][64];
    int b = blockIdx.x;              // 0..99
    int n = b / 25;
    int r0 = (b - n*25) * 64;
    int t = threadIdx.x, lane = t & 63, wv = t >> 6;
    int idx15 = lane & 15, kg = lane >> 4;

    const float* fb = fea + (size_t)n * 256 * 1600 + r0;
    #pragma unroll
    for (int i = 0; i < 8; ++i) {
        int flat = i*256 + t;
        int px4 = flat & 15, cp = flat >> 4;
        float4 v0 = *(const float4*)&fb[(size_t)(2*cp)*1600 + px4*4];
        float4 v1 = *(const float4*)&fb[(size_t)(2*cp+1)*1600 + px4*4];
        int x = (cp & 3) | (((cp >> 2) & 3) << 4);
        float a0[4] = {v0.x, v0.y, v0.z, v0.w};
        float a1[4] = {v1.x, v1.y, v1.z, v1.w};
        #pragma unroll
        for (int j = 0; j < 4; ++j) {
            unsigned int pk = (unsigned int)f2bf(a0[j]) | ((unsigned int)f2bf(a1[j]) << 16);
            lds[cp*64 + ((px4*4 + j) ^ x)] = pk;
        }
    }

    bf16x8 A[2][8];
    #pragma unroll
    for (int mi = 0; mi < 2; ++mi) {
        const u16* wrow = wpt + (size_t)(wv*32 + mi*16 + idx15)*256 + kg*8;
        #pragma unroll
        for (int ks = 0; ks < 8; ++ks)
            A[mi][ks] = *(const bf16x8*)(wrow + ks*32);
    }
    __syncthreads();

    f32x4 acc[2][4];
    #pragma unroll
    for (int mi = 0; mi < 2; ++mi)
        #pragma unroll
        for (int nt = 0; nt < 4; ++nt) acc[mi][nt] = (f32x4){0.f,0.f,0.f,0.f};

    #pragma unroll
    for (int ks = 0; ks < 8; ++ks) {
        #pragma unroll
        for (int nt = 0; nt < 4; ++nt) {
            union { unsigned int u[4]; bf16x8 v; } bw;
            #pragma unroll
            for (int w = 0; w < 4; ++w) {
                int cp = ks*16 + kg*4 + w;
                int x = (cp & 3) | (((cp >> 2) & 3) << 4);
                bw.u[w] = lds[cp*64 + ((nt*16 + idx15) ^ x)];
            }
            acc[0][nt] = __builtin_amdgcn_mfma_f32_16x16x32_bf16(A[0][ks], bw.v, acc[0][nt], 0, 0, 0);
            acc[1][nt] = __builtin_amdgcn_mfma_f32_16x16x32_bf16(A[1][ks], bw.v, acc[1][nt], 0, 0, 0);
        }
    }

    #pragma unroll
    for (int nt = 0; nt < 4; ++nt) {
        float sq = 0.f;
        #pragma unroll
        for (int mi = 0; mi < 2; ++mi)
            #pragma unroll
            for (int r = 0; r < 4; ++r) sq += acc[mi][nt][r]*acc[mi][nt][r];
        sq += __shfl_xor(sq, 16);
        sq += __shfl_xor(sq, 32);
        if (kg == 0) nrm[wv][nt*16 + idx15] = sq;
    }
    __syncthreads();

    #pragma unroll
    for (int nt = 0; nt < 4; ++nt) {
        int px = nt*16 + idx15;
        float tot = nrm[0][px] + nrm[1][px] + nrm[2][px] + nrm[3][px];
        float scale = 1.f / fmaxf(sqrtf(tot), 1e-12f);
        int r = r0 + px;
        int yy = r / 40, xx = r - yy*40;
        int row = ((yy/10*4 + xx/10)*4 + n)*100 + (yy%10)*10 + (xx%10);
        unsigned int* dst = (unsigned int*)(feat + (size_t)row*128) + wv*16 + kg*2;
        #pragma unroll
        for (int mi = 0; mi < 2; ++mi) {
            #pragma unroll
            for (int pr = 0; pr < 2; ++pr) {
                unsigned int pk = (unsigned int)f2bf(acc[mi][nt][2*pr]*scale)
                                | ((unsigned int)f2bf(acc[mi][nt][2*pr+1]*scale) << 16);
                dst[mi*8 + pr] = pk;
            }
        }
    }
}

// ---------------- EMA scatter: coalesced tile-transpose + 1 atomicMax/block ----------------
__global__ __launch_bounds__(256) void ema_scatter(
    const float* __restrict__ ema, u16* __restrict__ feat,
    unsigned int* __restrict__ maxn)
{
    __shared__ float lds[128*64];    // 32 KB, col = pxl ^ ((c>>5)<<3)
    int b = blockIdx.x;              // 0..99
    int n = b / 25;
    int r0 = (b - n*25) * 64;
    int t = threadIdx.x, lane = t & 63, wv = t >> 6;

    const float* src = ema + ((size_t)n*128 + wv*32)*1600 + r0 + lane;
    int scol = lane ^ (wv << 3);
    #pragma unroll
    for (int cc = 0; cc < 32; ++cc)
        lds[(wv*32 + cc)*64 + scol] = src[(size_t)cc*1600];
    __syncthreads();

    int pxl = t >> 2, cq = t & 3;
    int r = r0 + pxl;
    int yy = r / 40, xx = r - yy*40;
    int row = 6400 + ((yy/10*4 + xx/10)*4 + n)*100 + (yy%10)*10 + (xx%10);
    int rcol = pxl ^ (cq << 3);
    float sq = 0.f;
    unsigned int pk[16];
    #pragma unroll
    for (int i = 0; i < 16; ++i) {
        float v0 = lds[(cq*32 + 2*i)*64 + rcol];
        float v1 = lds[(cq*32 + 2*i + 1)*64 + rcol];
        sq += v0*v0 + v1*v1;
        pk[i] = (unsigned int)f2bf(v0) | ((unsigned int)f2bf(v1) << 16);
    }
    u16* dst = feat + (size_t)row*128 + cq*32;
    #pragma unroll
    for (int i = 0; i < 4; ++i)
        *(uint4*)&((unsigned int*)dst)[i*4] = *(uint4*)&pk[i*4];

    sq += __shfl_xor(sq, 1);
    sq += __shfl_xor(sq, 2);
    float mx = sq;
    #pragma unroll
    for (int off = 4; off < 64; off <<= 1) mx = fmaxf(mx, __shfl_xor(mx, off));
    __shared__ float red[4];
    if (lane == 0) red[wv] = mx;
    __syncthreads();
    if (t == 0)
        atomicMax(maxn, __float_as_uint(fmaxf(fmaxf(red[0], red[1]),
                                              fmaxf(red[2], red[3]))));
}

// ---------------- class feature sums + label-1 count ----------------
__global__ __launch_bounds__(256) void class_sum(
    const u16* __restrict__ feat, const int* __restrict__ lab,
    float* __restrict__ csum, float* __restrict__ acc)
{
    int t = threadIdx.x;
    int chp = t & 63;        // channel pair (2*chp, 2*chp+1)
    int s   = t >> 6;        // 0..3
    int r0 = blockIdx.x * 400;
    float s00=0.f, s01=0.f, s10=0.f, s11=0.f;
    float c1 = 0.f;
    for (int i = s; i < 400; i += 4) {
        int row = r0 + i;
        unsigned int pk = ((const unsigned int*)feat)[(size_t)row*64 + chp];
        float v0 = __uint_as_float(pk << 16);
        float v1 = __uint_as_float(pk & 0xffff0000u);
        int la = lab[row];
        if (la) { s10 += v0; s11 += v1; }
        else    { s00 += v0; s01 += v1; }
        if (chp == 0) c1 += (float)la;
    }
    __shared__ float red[4][256];
    __shared__ float cbuf[4];
    red[s][chp*4+0] = s00; red[s][chp*4+1] = s01;
    red[s][chp*4+2] = s10; red[s][chp*4+3] = s11;
    if (chp == 0) cbuf[s] = c1;
    __syncthreads();
    if (s == 0) {
        #pragma unroll
        for (int k = 0; k < 4; ++k) {
            float v = red[0][chp*4+k] + red[1][chp*4+k] + red[2][chp*4+k] + red[3][chp*4+k];
            int cls = k >> 1, par = k & 1;
            atomicAdd(&csum[cls*128 + 2*chp + par], v);
        }
    }
    if (t == 0)
        atomicAdd(&acc[8], cbuf[0]+cbuf[1]+cbuf[2]+cbuf[3]);
}

// ---------------- contrastive: MFMA streaming denominator-only GEMM ----------------
__global__ __launch_bounds__(256) void contrast_sE(
    const u16* __restrict__ feat, const unsigned int* __restrict__ maxn,
    float* __restrict__ partials)
{
    int js = blockIdx.x;      // 0..7
    int p  = blockIdx.y;      // 0..63
    int t = threadIdx.x, lane = t & 63, wv = t >> 6;
    int idx15 = lane & 15;
    int kg = lane >> 4;

    float M = 2.f * sqrtf(__uint_as_float(*maxn)) + 4.f;
    float M2 = M * 1.44269504f;

    bf16x8 A[2][4];
    bf16x8 zz = {0,0,0,0,0,0,0,0};
    #pragma unroll
    for (int mi = 0; mi < 2; ++mi) {
        int m = wv + mi*4;
        #pragma unroll
        for (int c = 0; c < 4; ++c) {
            int a = 16*m + idx15;
            A[mi][c] = (m < 7 && a < 100)
                ? *(const bf16x8*)&feat[(size_t)(p*100 + a)*128 + c*32 + kg*8]
                : zz;
        }
    }

    int jbase = js * 1600;
    float sE[8] = {};

    for (int jt = 0; jt < 100; ++jt) {
        int jrow = jbase + jt*16;
        bf16x8 B[4];
        #pragma unroll
        for (int c = 0; c < 4; ++c)
            B[c] = *(const bf16x8*)&feat[(size_t)(jrow + idx15)*128 + c*32 + kg*8];
        #pragma unroll
        for (int mi = 0; mi < 2; ++mi) {
            int m = wv + mi*4;
            if (m < 7) {
                f32x4 C = {0.f, 0.f, 0.f, 0.f};
                #pragma unroll
                for (int c = 0; c < 4; ++c)
                    C = __builtin_amdgcn_mfma_f32_16x16x32_bf16(A[mi][c], B[c], C, 0, 0, 0);
                #pragma unroll
                for (int r = 0; r < 4; ++r)
                    sE[mi*4+r] += exp2f(C[r] * 2.885390082f - M2);
            }
        }
    }

    #pragma unroll
    for (int mi = 0; mi < 2; ++mi) {
        int m = wv + mi*4;
        if (m < 7) {
            #pragma unroll
            for (int r = 0; r < 4; ++r) {
                float s = sE[mi*4+r];
                #pragma unroll
                for (int off = 1; off < 16; off <<= 1)
                    s += __shfl_xor(s, off);
                if (idx15 == 0) {
                    int a = 16*m + 4*kg + r;
                    partials[((size_t)p*8 + js)*112 + a] = s;
                }
            }
        }
    }
}

// ---------------- merge: LSE + positive-sum via class sums ----------------
__global__ __launch_bounds__(128) void merge_contrast(
    const float* __restrict__ partials, const float* __restrict__ fc_cnt,
    const unsigned int* __restrict__ maxn, const u16* __restrict__ feat,
    const int* __restrict__ lab, const float* __restrict__ csum,
    float* __restrict__ acc)
{
    int p = blockIdx.x, t = threadIdx.x;
    float pa = 0.f;
    if (t < 100) {
        float s = 0.f;
        #pragma unroll
        for (int js = 0; js < 8; ++js)
            s += partials[((size_t)p*8 + js)*112 + t];
        int row = p*100 + t;
        int la = lab[row];
        const float* Sv = csum + la*128;
        const unsigned int* av = (const unsigned int*)(feat + (size_t)row*128);
        float dp = 0.f;
        #pragma unroll
        for (int i = 0; i < 64; ++i) {
            unsigned int pk = av[i];
            dp += __uint_as_float(pk << 16) * Sv[2*i]
                + __uint_as_float(pk & 0xffff0000u) * Sv[2*i+1];
        }
        float N1 = acc[8];
        float cnt = la ? N1 : (12800.f - N1);
        float M = 2.f * sqrtf(__uint_as_float(*maxn)) + 4.f;
        pa = M + logf(s) - 2.f * dp / fmaxf(cnt, 1.f);
    }
    #pragma unroll
    for (int off = 32; off; off >>= 1) pa += __shfl_down(pa, off);
    __shared__ float w2[2];
    if ((t & 63) == 0) w2[t >> 6] = pa;
    __syncthreads();
    if (t == 0) {
        float loss_p = (w2[0] + w2[1]) / 100.f;
        float fcv = fc_cnt[p] / 100.f;
        float inc = ((fcv > 0.1f) && (fcv < 0.9f)) ? 0.f : 1.f;
        atomicAdd(&acc[5], loss_p * inc);
        atomicAdd(&acc[6], inc);
    }
}

// ---------------- final combine ----------------
__global__ void final_kernel(const float* __restrict__ acc,
                             const int* __restrict__ epoch_p,
                             float* __restrict__ out)
{
    if (threadIdx.x == 0 && blockIdx.x == 0) {
        float loss_sup = acc[0] / fmaxf(acc[1], 1.f);
        int epoch = *epoch_p;
        float loss = loss_sup;
        if (epoch >= 5) {
            float contr = acc[5] / fmaxf(acc[6], 1.f);
            float cons  = acc[3] / fmaxf(acc[4], 1.f);
            float ent   = acc[2] / 6400.f;
            float ramp  = fminf(fmaxf((float)epoch / 40.f, 0.f), 1.f);
            float d = 1.f - ramp;
            float cons_w = expf(-5.f * d * d);
            loss = loss_sup + 0.1f * contr + cons_w * cons + 0.01f * ent;
        }
        out[0] = loss;
    }
}

extern "C" void kernel_launch(void* const* d_in, const int* in_sizes, int n_in,
                              void* d_out, int out_size, void* d_ws, size_t ws_size,
                              hipStream_t stream)
{
    const float* x_l      = (const float*)d_in[0];
    const int*   y_l      = (const int*)  d_in[1];
    const float* x_ul     = (const float*)d_in[2];
    const int*   epoch    = (const int*)  d_in[3];
    const float* proj_ema = (const float*)d_in[4];
    const float* z_ema    = (const float*)d_in[5];
    const float* W1       = (const float*)d_in[6];
    const float* W2       = (const float*)d_in[7];
    const float* W3       = (const float*)d_in[8];
    const float* Wc       = (const float*)d_in[9];
    const float* bc       = (const float*)d_in[10];
    const float* Wp       = (const float*)d_in[11];
    float* out = (float*)d_out;
    float* ws  = (float*)d_ws;

    u16*   fea1b = (u16*)(ws + WS_FEA1B);
    u16*   fea2b = (u16*)(ws + WS_FEA2B);
    float* fea3  = ws + WS_FEA3;
    float* zls   = ws + WS_ZLS;
    float* zul   = ws + WS_ZUL;
    u16*   featB = (u16*)(ws + WS_FEATB);
    int*   labA  = (int*)(ws + WS_LAB);
    float* part  = ws + WS_PART;
    float* acc   = ws + WS_ACC;
    float* fc    = ws + WS_FC;
    float* csum  = ws + WS_CSUM;
    u16*   wt2   = (u16*)(ws + WS_WT2);
    u16*   wt3   = (u16*)(ws + WS_WT3);
    u16*   wpt   = (u16*)(ws + WS_WPT);
    unsigned int* maxn = (unsigned int*)(acc + 7);

    // zero acc(16) + fc(64) + csum(256): contiguous 336 floats
    hipMemsetAsync(acc, 0, 336 * sizeof(float), stream);
    hipMemsetAsync(zls, 0, 25600 * sizeof(float), stream);   // zls + zul

    wtrans<<<1568, 256, 0, stream>>>(W2, W3, Wp, wt2, wt3, wpt);

    // ---- both branches batched (n 0..3 labeled, 4..7 unlabeled) ----
    conv1_k<<<dim3(160, 8), 256, 0, stream>>>(x_l, x_ul, W1, fea1b);
    conv3x3_mfma<64,128,160,80,true><<<dim3(100, 2, 8), 256, 0, stream>>>(fea1b, wt2, fea2b, nullptr);
    conv3x3_mfma<128,256,80,40,false><<<dim3(25, 4, 8), 256, 0, stream>>>(fea2b, wt3, nullptr, fea3);
    conv1x1_cls<<<dim3(50, 8), 256, 0, stream>>>(fea3, Wc, zls);

    loss_sup_kernel<<<256, 256, 0, stream>>>(zls, y_l, bc, acc);
    ul_small_kernel<<<25, 256, 0, stream>>>(zul, z_ema, bc, labA, acc, fc);

    proj_mfma<<<100, 256, 0, stream>>>(fea3 + 4*409600, wpt, featB);
    ema_scatter<<<100, 256, 0, stream>>>(proj_ema, featB, maxn);
    class_sum<<<32, 256, 0, stream>>>(featB, labA, csum, acc);

    contrast_sE<<<dim3(8, 64), 256, 0, stream>>>(featB, maxn, part);
    merge_contrast<<<64, 128, 0, stream>>>(part, fc, maxn, featB, labA, csum, acc);
    final_kernel<<<1, 64, 0, stream>>>(acc, epoch, out);
}